// Round 8
// baseline (2985.664 us; speedup 1.0000x reference)
//
#include <hip/hip_runtime.h>
#include <hip/hip_bf16.h>
#include <math.h>

typedef short bf16x8 __attribute__((ext_vector_type(8)));
typedef float f32x4  __attribute__((ext_vector_type(4)));

__device__ __forceinline__ short f2bf(float f){
  unsigned u = __builtin_bit_cast(unsigned, f);
  u = u + 0x7FFFu + ((u >> 16) & 1u);
  return (short)(u >> 16);
}
__device__ __forceinline__ float bf2f(short h){
  unsigned u = ((unsigned)(unsigned short)h) << 16;
  return __builtin_bit_cast(float, u);
}
__device__ __forceinline__ float sigm(float x){ return 1.f/(1.f + __expf(-x)); }
__device__ __forceinline__ float tanh_f(float x){ return 2.f/(1.f + __expf(-2.f*x)) - 1.f; }

// f32 -> OCP e4m3fn with RNE (for weight quantization in prep)
__device__ __forceinline__ unsigned char f2e4m3(float f){
  unsigned u = __builtin_bit_cast(unsigned, f);
  unsigned s = (u >> 24) & 0x80u;
  float af = fabsf(f);
  if (!(af < 448.f)) return (unsigned char)(s | 0x7E);
  if (af < 0.015625f){
    int q = (int)(af * 512.f + 0.5f);
    return (unsigned char)(s | (unsigned)q);
  }
  int e = (int)((u >> 23) & 0xff) - 127;
  unsigned m = u & 0x7fffffu;
  unsigned mant = m >> 20;
  unsigned rem = m & 0xfffffu;
  if (rem > 0x80000u || (rem == 0x80000u && (mant & 1u))) mant++;
  if (mant == 8u){ mant = 0u; e++; if (e > 8) return (unsigned char)(s | 0x7E); }
  return (unsigned char)(s | ((unsigned)(e + 7) << 3) | mant);
}

// HW packed f32->fp8 (e4m3fn on gfx950), byte0=a, byte1=b
__device__ __forceinline__ unsigned cvt2_fp8(float a, float b){
  unsigned r;
  asm volatile("v_cvt_pk_fp8_f32 %0, %1, %2" : "=v"(r) : "v"(a), "v"(b));
  return r;
}

// LDS-only barrier: waits LDS ops, leaves global loads/stores in flight
__device__ __forceinline__ void lds_barrier(){
  asm volatile("s_waitcnt lgkmcnt(0)" ::: "memory");
  __builtin_amdgcn_s_barrier();
  __builtin_amdgcn_sched_barrier(0);
}

// Opaque 8B global load: cannot be rematerialized/CSE'd -> stays register-resident.
__device__ __forceinline__ long gload8(const void* p){
  long r;
  asm volatile("global_load_dwordx2 %0, %1, off" : "=v"(r) : "v"(p));
  return r;
}

#define MFMA(a,b,c)  __builtin_amdgcn_mfma_f32_16x16x32_bf16((a),(b),(c),0,0,0)
#define MFMA8(a,b,c) __builtin_amdgcn_mfma_f32_16x16x32_fp8_fp8((a),(b),(c),0,0,0)

// ---------------- prep kernels ----------------

__global__ void prep_convw(const float* __restrict__ w, const float* __restrict__ cb,
                           const float* __restrict__ g, const float* __restrict__ bb,
                           const float* __restrict__ m, const float* __restrict__ v,
                           short* __restrict__ wT, float* __restrict__ bias,
                           int O, int I, int Cpad){
  int idx = blockIdx.x*blockDim.x + threadIdx.x;
  int total = 7*O*Cpad;
  if (idx < total){
    int kt = idx / (O*Cpad);
    int rem = idx - kt*O*Cpad;
    int n = rem / Cpad;
    int c = rem - n*Cpad;
    float s = g[n] * rsqrtf(v[n] + 1e-5f);
    float val = (c < I) ? w[((size_t)n*I + c)*7 + kt] * s : 0.f;
    wT[idx] = f2bf(val);
  }
  if (idx < O){
    float s = g[idx] * rsqrtf(v[idx] + 1e-5f);
    bias[idx] = (cb[idx] - m[idx]) * s + bb[idx];
  }
}

__global__ void cast_f32_bf16(const float* __restrict__ src, short* __restrict__ dst, int n){
  int i = blockIdx.x*blockDim.x + threadIdx.x;
  int stride = gridDim.x*blockDim.x;
  for (; i < n; i += stride) dst[i] = f2bf(src[i]);
}

__global__ void add_f32(const float* __restrict__ a, const float* __restrict__ b, float* __restrict__ c, int n){
  int i = blockIdx.x*blockDim.x + threadIdx.x;
  if (i < n) c[i] = a[i] + b[i];
}

// in [e][K][N] f32 -> out [e][N][K] bf16
__global__ void transp_k(const float* __restrict__ in, short* __restrict__ out, int E, int K, int N){
  int idx = blockIdx.x*blockDim.x + threadIdx.x;
  int total = E*K*N;
  if (idx >= total) return;
  int e = idx / (N*K);
  int rem = idx - e*N*K;
  int n = rem / K;
  int k = rem - n*K;
  out[idx] = f2bf(in[((size_t)e*K + k)*N + n]);
}

// quantize ALL whh rows (i:0-255, f:256-511, g:512-767, o:768-1023) to fp8 e4m3, per-row scale.
// wq8: [4][256][256] bytes; inv_s: [4][256] floats (gate = inv_s * acc)
__global__ __launch_bounds__(64) void quant_whh(const float* __restrict__ whh,
                                                unsigned char* __restrict__ wq8,
                                                float* __restrict__ inv_s){
  const int rb = blockIdx.x;          // 0..1023, natural i,f,g,o order
  const int lane = threadIdx.x;
  const float* wr = whh + (size_t)rb*256;
  float v4[4];
  float mx = 0.f;
#pragma unroll
  for (int j = 0; j < 4; ++j){ v4[j] = wr[lane*4 + j]; mx = fmaxf(mx, fabsf(v4[j])); }
#pragma unroll
  for (int off = 32; off >= 1; off >>= 1) mx = fmaxf(mx, __shfl_xor(mx, off));
  float s = (mx > 0.f) ? (448.f / mx) : 1.f;
  if (lane == 0) inv_s[rb] = (mx > 0.f) ? (mx / 448.f) : 0.f;
  unsigned w = 0;
#pragma unroll
  for (int j = 0; j < 4; ++j) w |= ((unsigned)f2e4m3(v4[j]*s)) << (8*j);
  *(unsigned*)(wq8 + (size_t)rb*256 + lane*4) = w;
}

// ---------------- conv1: x(512,80,800)f32 -> a1[b][400][128] bf16 ----------------
#define C1_ROWS 86
#define C1_PITCH 104
__global__ __launch_bounds__(512) void conv1_k(const float* __restrict__ x, const short* __restrict__ wT,
                                               const float* __restrict__ bias, short* __restrict__ out){
  __shared__ short At[C1_ROWS*C1_PITCH];
  const int b = blockIdx.y;
  const int t0 = blockIdx.x * 80;
  const int tid = threadIdx.x;
  for (int i = tid; i < C1_ROWS*C1_PITCH; i += 512) At[i] = 0;
  __syncthreads();
  for (int idx = tid; idx < 80*C1_ROWS; idx += 512){
    int c = idx / C1_ROWS, i = idx - c*C1_ROWS;
    int t = t0 - 3 + i;
    float v = (t >= 0 && t < 800) ? x[((size_t)b*80 + c)*800 + t] : 0.f;
    At[i*C1_PITCH + c] = f2bf(v);
  }
  __syncthreads();
  const int lane = tid & 63, wave = tid >> 6;
  const int l15 = lane & 15, lq = lane >> 4;
  const int col = wave*16 + l15;
  f32x4 z = {0.f,0.f,0.f,0.f};
  f32x4 acc[5] = {z,z,z,z,z};
  for (int kt = 0; kt < 7; ++kt){
    for (int ks = 0; ks < 3; ++ks){
      bf16x8 bf = *(const bf16x8*)(wT + ((size_t)(kt*128 + col))*96 + ks*32 + lq*8);
#pragma unroll
      for (int mf = 0; mf < 5; ++mf){
        bf16x8 af = *(const bf16x8*)(At + (mf*16 + l15 + kt)*C1_PITCH + ks*32 + lq*8);
        acc[mf] = MFMA(af, bf, acc[mf]);
      }
    }
  }
  const float bs = bias[col];
#pragma unroll
  for (int mf = 0; mf < 5; ++mf){
    float v0 = fmaxf(acc[mf][0]+bs, 0.f), v1 = fmaxf(acc[mf][1]+bs, 0.f);
    float v2 = fmaxf(acc[mf][2]+bs, 0.f), v3 = fmaxf(acc[mf][3]+bs, 0.f);
    int tp = (t0 + mf*16 + lq*4) >> 1;
    out[((size_t)b*400 + tp  )*128 + col] = f2bf(fmaxf(v0,v1));
    out[((size_t)b*400 + tp+1)*128 + col] = f2bf(fmaxf(v2,v3));
  }
}

// ---------------- conv2: a1[b][400][128] -> a2[b][200][256] bf16 ----------------
#define C2_ROWS 86
#define C2_PITCH 136
__global__ __launch_bounds__(512) void conv2_k(const short* __restrict__ a1, const short* __restrict__ wT,
                                               const float* __restrict__ bias, short* __restrict__ out){
  __shared__ short At[C2_ROWS*C2_PITCH];
  const int b = blockIdx.y;
  const int t0 = blockIdx.x * 80;
  const int tid = threadIdx.x;
  bf16x8 zb = {0,0,0,0,0,0,0,0};
  for (int idx = tid; idx < C2_ROWS*16; idx += 512){
    int i = idx >> 4, c8 = idx & 15;
    int t = t0 - 3 + i;
    bf16x8 v = zb;
    if (t >= 0 && t < 400) v = *(const bf16x8*)(a1 + ((size_t)b*400 + t)*128 + c8*8);
    *(bf16x8*)(At + i*C2_PITCH + c8*8) = v;
  }
  __syncthreads();
  const int lane = tid & 63, wave = tid >> 6;
  const int l15 = lane & 15, lq = lane >> 4;
  f32x4 z = {0.f,0.f,0.f,0.f};
  f32x4 acc[5][2];
#pragma unroll
  for (int mf = 0; mf < 5; ++mf){ acc[mf][0] = z; acc[mf][1] = z; }
  for (int kt = 0; kt < 7; ++kt){
    for (int ks = 0; ks < 4; ++ks){
      bf16x8 bf0 = *(const bf16x8*)(wT + ((size_t)(kt*256 + wave*32      + l15))*128 + ks*32 + lq*8);
      bf16x8 bf1 = *(const bf16x8*)(wT + ((size_t)(kt*256 + wave*32 + 16 + l15))*128 + ks*32 + lq*8);
#pragma unroll
      for (int mf = 0; mf < 5; ++mf){
        bf16x8 af = *(const bf16x8*)(At + (mf*16 + l15 + kt)*C2_PITCH + ks*32 + lq*8);
        acc[mf][0] = MFMA(af, bf0, acc[mf][0]);
        acc[mf][1] = MFMA(af, bf1, acc[mf][1]);
      }
    }
  }
#pragma unroll
  for (int fi = 0; fi < 2; ++fi){
    int col = wave*32 + fi*16 + l15;
    float bs = bias[col];
#pragma unroll
    for (int mf = 0; mf < 5; ++mf){
      float v0 = fmaxf(acc[mf][fi][0]+bs, 0.f), v1 = fmaxf(acc[mf][fi][1]+bs, 0.f);
      float v2 = fmaxf(acc[mf][fi][2]+bs, 0.f), v3 = fmaxf(acc[mf][fi][3]+bs, 0.f);
      int tp = (t0 + mf*16 + lq*4) >> 1;
      out[((size_t)b*200 + tp  )*256 + col] = f2bf(fmaxf(v0,v1));
      out[((size_t)b*200 + tp+1)*256 + col] = f2bf(fmaxf(v2,v3));
    }
  }
}

// ---------------- xg GEMM -> permuted xgp layout (512-thread lstm) ----------------
// xgp (bf16): [gi][t][blk][tid512][8], elem = fi*4 + r
__global__ __launch_bounds__(512) void xg_k(const short* __restrict__ A, const short* __restrict__ W,
                                            const float* __restrict__ bias, short* __restrict__ xg, int mode){
  __shared__ short At[128*264];
  const int M0 = blockIdx.x * 128;
  const int gi = blockIdx.y;
  const int N0 = gi * 256;
  const int tid = threadIdx.x;
  const int t  = M0 >> 9;
  const int bl = M0 & 511;
  for (int idx = tid; idx < 128*32; idx += 512){
    int i = idx >> 5, c8 = idx & 31;
    int arow = (mode == 0) ? ((bl + i)*200 + t) : (M0 + i);
    *(bf16x8*)(At + i*264 + c8*8) = *(const bf16x8*)(A + (size_t)arow*256 + c8*8);
  }
  __syncthreads();
  const int lane = tid & 63, wave = tid >> 6, l15 = lane & 15, lq = lane >> 4;
  f32x4 z = {0.f,0.f,0.f,0.f};
  f32x4 acc[8][2];
#pragma unroll
  for (int mf = 0; mf < 8; ++mf){ acc[mf][0] = z; acc[mf][1] = z; }
  for (int ks = 0; ks < 8; ++ks){
    bf16x8 bf0 = *(const bf16x8*)(W + ((size_t)(N0 + wave*32      + l15))*256 + ks*32 + lq*8);
    bf16x8 bf1 = *(const bf16x8*)(W + ((size_t)(N0 + wave*32 + 16 + l15))*256 + ks*32 + lq*8);
#pragma unroll
    for (int mf = 0; mf < 8; ++mf){
      bf16x8 af = *(const bf16x8*)(At + (mf*16 + l15)*264 + ks*32 + lq*8);
      acc[mf][0] = MFMA(af, bf0, acc[mf][0]);
      acc[mf][1] = MFMA(af, bf1, acc[mf][1]);
    }
  }
  const int blkbase = bl >> 4;
  const float bs0 = bias[N0 + wave*32 + l15];
  const float bs1 = bias[N0 + wave*32 + 16 + l15];
#pragma unroll
  for (int mf = 0; mf < 8; ++mf){
    bf16x8 vch;
#pragma unroll
    for (int r = 0; r < 4; ++r){
      vch[r]     = f2bf(acc[mf][0][r] + bs0);
      vch[4 + r] = f2bf(acc[mf][1][r] + bs1);
    }
    size_t chunk = (((size_t)gi*200 + t)*32 + blkbase + mf)*512 + wave*64 + lq*16 + l15;
    *(bf16x8*)(xg + chunk*8) = vch;
  }
}

// ---------------- LSTM recurrence v8: ALL-fp8 (i,g LDS; o regs; f L2-streamed fp8) ----------------
// 512 threads, 8 waves x 32 cols. h kept fp8-only in LDS double buffer. 1 barrier/step.
__global__ __launch_bounds__(512)
void lstm_k(const short* __restrict__ xgp,
            const unsigned char* __restrict__ wq8, const float* __restrict__ inv_s,
            short* __restrict__ hseq, float* __restrict__ feat, int mode){
  __shared__ __align__(16) unsigned char wq[2*256*256];   // i, g (XOR-swizzled rows)
  __shared__ __align__(16) unsigned char h8l[2][16*264];  // fp8 h double buffer
  const int blk = blockIdx.x;
  const int b0 = blk * 16;
  const int tid = threadIdx.x, lane = tid & 63, wave = tid >> 6;
  const int l15 = lane & 15, lq = lane >> 4;
  const int j0 = wave * 32;
  const int swz = (l15 & 7) << 4;

  for (int i = tid; i < 16*264; i += 512) h8l[0][i] = 0;
  // stage i (rows 0-255) and g (rows 512-767) fp8 weights into LDS (swizzled)
  for (int idx = tid; idx < 2*256*16; idx += 512){
    int gg = idx >> 12;
    int rem = idx & 4095;
    int row = rem >> 4, c16 = (rem & 15) << 4;
    uint4 v = *(const uint4*)(wq8 + ((size_t)(gg*512 + row))*256 + c16);
    *(uint4*)(&wq[gg*65536 + row*256 + (c16 ^ ((row & 7) << 4))]) = v;
  }
  // o-gate fp8 fragments pinned in registers: 16 x 8B = 32 VGPRs
  long oreg[2][8];
#pragma unroll
  for (int fi = 0; fi < 2; ++fi)
#pragma unroll
    for (int kk = 0; kk < 8; ++kk)
      oreg[fi][kk] = gload8(wq8 + ((size_t)(768 + j0 + fi*16 + l15))*256 + kk*32 + lq*8);
  // dequant scales
  float is_i[2], is_f[2], is_g[2], is_o[2];
#pragma unroll
  for (int fi = 0; fi < 2; ++fi){
    int col = j0 + fi*16 + l15;
    is_i[fi] = inv_s[col];
    is_f[fi] = inv_s[256 + col];
    is_g[fi] = inv_s[512 + col];
    is_o[fi] = inv_s[768 + col];
  }
  asm volatile("s_waitcnt vmcnt(0)" ::: "memory");

  float c[2][4];
#pragma unroll
  for (int fi=0; fi<2; ++fi)
#pragma unroll
    for (int r=0; r<4; ++r) c[fi][r] = 0.f;

  __syncthreads();

  const size_t GI = (size_t)200*32*512*8;  // per-gi stride in shorts
  bf16x8 xq0, xq1, xq2, xq3;
  {
    const short* p = xgp + (((size_t)0*32 + blk)*512 + tid)*8;
    xq0 = *(const bf16x8*)(p);
    xq1 = *(const bf16x8*)(p + GI);
    xq2 = *(const bf16x8*)(p + 2*GI);
    xq3 = *(const bf16x8*)(p + 3*GI);
  }

  const unsigned char* fbase8 = wq8 + (size_t)256*256;  // f-gate rows, fp8
  int cur = 0;

  for (int t = 0; t < 200; ++t){
    const unsigned char* h8c = h8l[cur];
    f32x4 zz = {0.f,0.f,0.f,0.f};
    f32x4 acc[4][2];
#pragma unroll
    for (int gi=0; gi<4; ++gi){ acc[gi][0] = zz; acc[gi][1] = zz; }
#pragma unroll
    for (int kk = 0; kk < 8; ++kk){
      long wf0 = *(const long*)(fbase8 + ((size_t)(j0      + l15))*256 + kk*32 + lq*8);
      long wf1 = *(const long*)(fbase8 + ((size_t)(j0 + 16 + l15))*256 + kk*32 + lq*8);
      long av8 = *(const long*)(h8c + l15*264 + kk*32 + lq*8);
      int bo = (kk*32 + lq*8) ^ swz;
      long wi0 = *(const long*)(&wq[          (j0      + l15)*256 + bo]);
      long wi1 = *(const long*)(&wq[          (j0 + 16 + l15)*256 + bo]);
      long wg0 = *(const long*)(&wq[65536 +   (j0      + l15)*256 + bo]);
      long wg1 = *(const long*)(&wq[65536 +   (j0 + 16 + l15)*256 + bo]);
      acc[0][0] = MFMA8(av8, wi0, acc[0][0]);
      acc[0][1] = MFMA8(av8, wi1, acc[0][1]);
      acc[1][0] = MFMA8(av8, wf0, acc[1][0]);
      acc[1][1] = MFMA8(av8, wf1, acc[1][1]);
      acc[2][0] = MFMA8(av8, wg0, acc[2][0]);
      acc[2][1] = MFMA8(av8, wg1, acc[2][1]);
      acc[3][0] = MFMA8(av8, oreg[0][kk], acc[3][0]);
      acc[3][1] = MFMA8(av8, oreg[1][kk], acc[3][1]);
    }
    short hnew[2][4];
    float hfv[2][4];
#pragma unroll
    for (int fi=0; fi<2; ++fi){
#pragma unroll
      for (int r=0; r<4; ++r){
        int e = fi*4 + r;
        float iv = acc[0][fi][r]*is_i[fi] + bf2f(xq0[e]);
        float fv = acc[1][fi][r]*is_f[fi] + bf2f(xq1[e]);
        float gv = acc[2][fi][r]*is_g[fi] + bf2f(xq2[e]);
        float ov = acc[3][fi][r]*is_o[fi] + bf2f(xq3[e]);
        float cs = sigm(fv)*c[fi][r] + sigm(iv)*tanh_f(gv);
        c[fi][r] = cs;
        float hv = sigm(ov)*tanh_f(cs);
        hfv[fi][r] = hv;
        hnew[fi][r] = f2bf(hv);
      }
    }
    if (t + 1 < 200){
      const short* p = xgp + (((size_t)(t+1)*32 + blk)*512 + tid)*8;
      xq0 = *(const bf16x8*)(p);
      xq1 = *(const bf16x8*)(p + GI);
      xq2 = *(const bf16x8*)(p + 2*GI);
      xq3 = *(const bf16x8*)(p + 3*GI);
    }
    // write new h (fp8 only) into the other buffer
    unsigned char* h8n = h8l[cur ^ 1];
#pragma unroll
    for (int fi=0; fi<2; ++fi){
      int col = j0 + fi*16 + l15;
      unsigned p01 = cvt2_fp8(hfv[fi][0], hfv[fi][1]);
      unsigned p23 = cvt2_fp8(hfv[fi][2], hfv[fi][3]);
      h8n[(lq*4+0)*264 + col] = (unsigned char)(p01 & 0xff);
      h8n[(lq*4+1)*264 + col] = (unsigned char)((p01 >> 8) & 0xff);
      h8n[(lq*4+2)*264 + col] = (unsigned char)(p23 & 0xff);
      h8n[(lq*4+3)*264 + col] = (unsigned char)((p23 >> 8) & 0xff);
    }
    if (mode == 0){
      short* hs = hseq + ((size_t)t*512 + b0)*256;
#pragma unroll
      for (int fi=0; fi<2; ++fi)
#pragma unroll
        for (int r=0; r<4; ++r)
          hs[(lq*4+r)*256 + j0 + fi*16 + l15] = hnew[fi][r];
    } else if (t == 199){
#pragma unroll
      for (int fi=0; fi<2; ++fi)
#pragma unroll
        for (int r=0; r<4; ++r)
          feat[(size_t)(b0 + lq*4 + r)*256 + j0 + fi*16 + l15] = bf2f(hnew[fi][r]);
    }
    lds_barrier();
    cur ^= 1;
  }
}

// ---------------- gating + feat cast ----------------
__global__ __launch_bounds__(64) void gating_k(const float* __restrict__ feat, const float* __restrict__ gw,
    const float* __restrict__ gb, const float* __restrict__ bg, const float* __restrict__ bb,
    const float* __restrict__ bm, const float* __restrict__ bv,
    float* __restrict__ gating, short* __restrict__ featb){
  const int b = blockIdx.x, lane = threadIdx.x;
  __shared__ float fr[256];
  __shared__ float lg[12];
  for (int i = lane; i < 256; i += 64){
    float v = feat[(size_t)b*256 + i];
    fr[i] = v;
    featb[(size_t)b*256 + i] = f2bf(v);
  }
  __syncthreads();
  if (lane < 12){
    float s = gb[lane];
    for (int k = 0; k < 256; ++k) s += fr[k]*gw[lane*256 + k];
    s = (s - bm[lane])*rsqrtf(bv[lane] + 1e-5f)*bg[lane] + bb[lane];
    lg[lane] = s;
  }
  __syncthreads();
  if (lane == 0){
    float mx = lg[0];
    for (int g = 1; g < 12; ++g) mx = fmaxf(mx, lg[g]);
    float den = 0.f, ex[12];
    for (int g = 0; g < 12; ++g){ ex[g] = __expf(lg[g]-mx); den += ex[g]; }
    for (int g = 0; g < 12; ++g) gating[b*12 + g] = ex[g]/den;
  }
}

// ---------------- MoE experts (atomic accumulate into moe) ----------------
__global__ __launch_bounds__(256) void moe_k(const short* __restrict__ featb, const short* __restrict__ w1t,
    const float* __restrict__ b1, const short* __restrict__ w2t, const float* __restrict__ b2,
    const float* __restrict__ gating, float* __restrict__ moe){
  __shared__ short eh[32*520];
  const int e = blockIdx.x;
  const int b0 = blockIdx.y * 32;
  const int tid = threadIdx.x, lane = tid & 63, wave = tid >> 6;
  const int l15 = lane & 15, lq = lane >> 4;
  f32x4 z = {0.f,0.f,0.f,0.f};
  f32x4 acc[2][8];
#pragma unroll
  for (int nf = 0; nf < 8; ++nf){ acc[0][nf] = z; acc[1][nf] = z; }
  for (int ks = 0; ks < 8; ++ks){
    bf16x8 af0 = *(const bf16x8*)(featb + ((size_t)(b0      + l15))*256 + ks*32 + lq*8);
    bf16x8 af1 = *(const bf16x8*)(featb + ((size_t)(b0 + 16 + l15))*256 + ks*32 + lq*8);
#pragma unroll
    for (int nf = 0; nf < 8; ++nf){
      bf16x8 bf = *(const bf16x8*)(w1t + ((size_t)(e*512 + wave*128 + nf*16 + l15))*256 + ks*32 + lq*8);
      acc[0][nf] = MFMA(af0, bf, acc[0][nf]);
      acc[1][nf] = MFMA(af1, bf, acc[1][nf]);
    }
  }
#pragma unroll
  for (int mf = 0; mf < 2; ++mf){
#pragma unroll
    for (int nf = 0; nf < 8; ++nf){
      int h = wave*128 + nf*16 + l15;
      float bb = b1[e*512 + h];
#pragma unroll
      for (int r = 0; r < 4; ++r){
        float v = acc[mf][nf][r] + bb;
        v = 0.5f*v*(1.f + erff(v*0.70710678118f));
        eh[(mf*16 + lq*4 + r)*520 + h] = f2bf(v);
      }
    }
  }
  __syncthreads();
  f32x4 a2c[2][4];
#pragma unroll
  for (int nf = 0; nf < 4; ++nf){ a2c[0][nf] = z; a2c[1][nf] = z; }
  for (int ks = 0; ks < 16; ++ks){
    bf16x8 af0 = *(const bf16x8*)(eh + (l15     )*520 + ks*32 + lq*8);
    bf16x8 af1 = *(const bf16x8*)(eh + (16 + l15)*520 + ks*32 + lq*8);
#pragma unroll
    for (int nf = 0; nf < 4; ++nf){
      bf16x8 bf = *(const bf16x8*)(w2t + ((size_t)(e*256 + wave*64 + nf*16 + l15))*512 + ks*32 + lq*8);
      a2c[0][nf] = MFMA(af0, bf, a2c[0][nf]);
      a2c[1][nf] = MFMA(af1, bf, a2c[1][nf]);
    }
  }
#pragma unroll
  for (int mf = 0; mf < 2; ++mf){
#pragma unroll
    for (int r = 0; r < 4; ++r){
      int b = b0 + mf*16 + lq*4 + r;
      float ge = gating[b*12 + e];
#pragma unroll
      for (int nf = 0; nf < 4; ++nf){
        int d = wave*64 + nf*16 + l15;
        atomicAdd(&moe[(size_t)b*256 + d], ge*(a2c[mf][nf][r] + b2[e*256 + d]));
      }
    }
  }
}

// ---------------- towers + head + sigmoid ----------------
__global__ __launch_bounds__(256) void tower_k(const float* __restrict__ moe,
    const float* f1sw, const float* f1sb, const float* f2sw, const float* f2sb,
    const float* f3sw, const float* f3sb,
    const float* f1pw, const float* f1pb, const float* f2pw, const float* f2pb,
    const float* f3pw, const float* f3pb,
    const float* hw, const float* hb, float* __restrict__ out){
  __shared__ float mt[16*256];
  __shared__ float h1[2][16][128];
  __shared__ float h2[2][16][64];
  __shared__ float h3[2][16];
  __shared__ float gl[16][2];
  const int b0 = blockIdx.x * 16;
  const int tid = threadIdx.x;
  for (int i = tid; i < 16*256; i += 256) mt[i] = moe[(size_t)b0*256 + i];
  __syncthreads();
  for (int idx = tid; idx < 4096; idx += 256){
    int tower = idx >> 11, b = (idx >> 7) & 15, n = idx & 127;
    const float* w = tower ? f1pw : f1sw;
    float s = (tower ? f1pb : f1sb)[n];
    for (int k = 0; k < 256; ++k) s += mt[b*256 + k]*w[n*256 + k];
    h1[tower][b][n] = fmaxf(s, 0.f);
  }
  __syncthreads();
  for (int idx = tid; idx < 2048; idx += 256){
    int tower = idx >> 10, b = (idx >> 6) & 15, n = idx & 63;
    const float* w = tower ? f2pw : f2sw;
    float s = (tower ? f2pb : f2sb)[n];
    for (int k = 0; k < 128; ++k) s += h1[tower][b][k]*w[n*128 + k];
    h2[tower][b][n] = fmaxf(s, 0.f);
  }
  __syncthreads();
  if (tid < 32){
    int tower = tid >> 4, b = tid & 15;
    const float* w = tower ? f3pw : f3sw;
    float s = (tower ? f3pb : f3sb)[0];
    for (int k = 0; k < 64; ++k) s += h2[tower][b][k]*w[k];
    h3[tower][b] = s;
  } else if (tid < 64){
    int i2 = tid - 32; int b = i2 >> 1, g = i2 & 1;
    float s = hb[g];
    for (int k = 0; k < 256; ++k) s += mt[b*256 + k]*hw[g*256 + k];
    gl[b][g] = s;
  }
  __syncthreads();
  if (tid < 16){
    int b = tid;
    float g0 = 1.f/(1.f + __expf(gl[b][1] - gl[b][0]));
    float val = g0*h3[0][b] + (1.f - g0)*h3[1][b];
    out[b0 + b] = 1.f/(1.f + __expf(-val));
  }
}

// ---------------- host ----------------
extern "C" void kernel_launch(void* const* d_in, const int* in_sizes, int n_in,
                              void* d_out, int out_size, void* d_ws, size_t ws_size,
                              hipStream_t stream){
  (void)in_sizes; (void)n_in; (void)out_size; (void)ws_size;
  const float* x       = (const float*)d_in[0];
  const float* conv1_w = (const float*)d_in[1];
  const float* conv1_b = (const float*)d_in[2];
  const float* bn1_g   = (const float*)d_in[3];
  const float* bn1_b   = (const float*)d_in[4];
  const float* bn1_m   = (const float*)d_in[5];
  const float* bn1_v   = (const float*)d_in[6];
  const float* conv2_w = (const float*)d_in[7];
  const float* conv2_b = (const float*)d_in[8];
  const float* bn2_g   = (const float*)d_in[9];
  const float* bn2_b   = (const float*)d_in[10];
  const float* bn2_m   = (const float*)d_in[11];
  const float* bn2_v   = (const float*)d_in[12];
  const float* wih0    = (const float*)d_in[13];
  const float* whh0    = (const float*)d_in[14];
  const float* bih0    = (const float*)d_in[15];
  const float* bhh0    = (const float*)d_in[16];
  const float* wih1    = (const float*)d_in[17];
  const float* whh1    = (const float*)d_in[18];
  const float* bih1    = (const float*)d_in[19];
  const float* bhh1    = (const float*)d_in[20];
  const float* gate_w  = (const float*)d_in[21];
  const float* gate_b  = (const float*)d_in[22];
  const float* gbn_g   = (const float*)d_in[23];
  const float* gbn_b   = (const float*)d_in[24];
  const float* gbn_m   = (const float*)d_in[25];
  const float* gbn_v   = (const float*)d_in[26];
  const float* exp_w1  = (const float*)d_in[27];
  const float* exp_b1  = (const float*)d_in[28];
  const float* exp_w2  = (const float*)d_in[29];
  const float* exp_b2  = (const float*)d_in[30];
  const float* fc1s_w  = (const float*)d_in[31];
  const float* fc1s_b  = (const float*)d_in[32];
  const float* fc2s_w  = (const float*)d_in[33];
  const float* fc2s_b  = (const float*)d_in[34];
  const float* fc3s_w  = (const float*)d_in[35];
  const float* fc3s_b  = (const float*)d_in[36];
  const float* fc1p_w  = (const float*)d_in[37];
  const float* fc1p_b  = (const float*)d_in[38];
  const float* fc2p_w  = (const float*)d_in[39];
  const float* fc2p_b  = (const float*)d_in[40];
  const float* fc3p_w  = (const float*)d_in[41];
  const float* fc3p_b  = (const float*)d_in[42];
  const float* head_w  = (const float*)d_in[43];
  const float* head_b  = (const float*)d_in[44];
  float* out = (float*)d_out;

  char* base = (char*)d_ws;
  size_t off = 0;
  auto alloc = [&](size_t nbytes)->void*{
    off = (off + 255) & ~(size_t)255;
    void* p = base + off;
    off += nbytes;
    return p;
  };
  short* w1T    = (short*)alloc((size_t)7*128*96*2);
  float* b1c    = (float*)alloc(128*4);
  short* w2T    = (short*)alloc((size_t)7*256*128*2);
  float* b2c    = (float*)alloc(256*4);
  short* wih0b  = (short*)alloc((size_t)1024*256*2);
  short* wih1b  = (short*)alloc((size_t)1024*256*2);
  float* bias0  = (float*)alloc(1024*4);
  float* bias1  = (float*)alloc(1024*4);
  unsigned char* wq8_0 = (unsigned char*)alloc((size_t)4*256*256);
  unsigned char* wq8_1 = (unsigned char*)alloc((size_t)4*256*256);
  float* invs0  = (float*)alloc(4*256*4);
  float* invs1  = (float*)alloc(4*256*4);
  short* eW1T   = (short*)alloc((size_t)12*512*256*2);
  short* eW2T   = (short*)alloc((size_t)12*256*512*2);
  short* featb  = (short*)alloc((size_t)512*256*2);
  float* gatingb= (float*)alloc((size_t)512*12*4);
  float* moebuf = (float*)alloc((size_t)512*256*4);
  float* featf  = (float*)alloc((size_t)512*256*4);
  short* a1     = (short*)alloc((size_t)512*400*128*2);
  short* a2     = (short*)alloc((size_t)512*200*256*2);
  short* xgbuf  = (short*)alloc((size_t)200*512*1024*2);
  short* h0seq  = a1;  // a1 dead after conv2

  // prep
  prep_convw<<<(7*128*96 + 255)/256, 256, 0, stream>>>(conv1_w, conv1_b, bn1_g, bn1_b, bn1_m, bn1_v, w1T, b1c, 128, 80, 96);
  prep_convw<<<(7*256*128 + 255)/256, 256, 0, stream>>>(conv2_w, conv2_b, bn2_g, bn2_b, bn2_m, bn2_v, w2T, b2c, 256, 128, 128);
  cast_f32_bf16<<<512, 256, 0, stream>>>(wih0, wih0b, 1024*256);
  cast_f32_bf16<<<512, 256, 0, stream>>>(wih1, wih1b, 1024*256);
  quant_whh<<<1024, 64, 0, stream>>>(whh0, wq8_0, invs0);
  quant_whh<<<1024, 64, 0, stream>>>(whh1, wq8_1, invs1);
  add_f32<<<4, 256, 0, stream>>>(bih0, bhh0, bias0, 1024);
  add_f32<<<4, 256, 0, stream>>>(bih1, bhh1, bias1, 1024);
  transp_k<<<(12*512*256 + 255)/256, 256, 0, stream>>>(exp_w1, eW1T, 12, 256, 512);
  transp_k<<<(12*256*512 + 255)/256, 256, 0, stream>>>(exp_w2, eW2T, 12, 512, 256);

  // pipeline
  conv1_k<<<dim3(10, 512), 512, 0, stream>>>(x, w1T, b1c, a1);
  conv2_k<<<dim3(5, 512), 512, 0, stream>>>(a1, w2T, b2c, a2);
  xg_k<<<dim3(800, 4), 512, 0, stream>>>(a2, wih0b, bias0, xgbuf, 0);
  lstm_k<<<32, 512, 0, stream>>>(xgbuf, wq8_0, invs0, h0seq, nullptr, 0);
  xg_k<<<dim3(800, 4), 512, 0, stream>>>(h0seq, wih1b, bias1, xgbuf, 1);
  lstm_k<<<32, 512, 0, stream>>>(xgbuf, wq8_1, invs1, nullptr, featf, 1);
  gating_k<<<512, 64, 0, stream>>>(featf, gate_w, gate_b, gbn_g, gbn_b, gbn_m, gbn_v, gatingb, featb);
  hipMemsetAsync(moebuf, 0, (size_t)512*256*4, stream);
  moe_k<<<dim3(12, 16), 256, 0, stream>>>(featb, eW1T, exp_b1, eW2T, exp_b2, gatingb, moebuf);
  tower_k<<<32, 256, 0, stream>>>(moebuf,
      fc1s_w, fc1s_b, fc2s_w, fc2s_b, fc3s_w, fc3s_b,
      fc1p_w, fc1p_b, fc2p_w, fc2p_b, fc3p_w, fc3p_b,
      head_w, head_b, out);
}

// Round 9
// 2553.404 us; speedup vs baseline: 1.1693x; 1.1693x over previous
//
#include <hip/hip_runtime.h>
#include <hip/hip_bf16.h>
#include <math.h>

typedef short bf16x8 __attribute__((ext_vector_type(8)));
typedef float f32x4  __attribute__((ext_vector_type(4)));

__device__ __forceinline__ short f2bf(float f){
  unsigned u = __builtin_bit_cast(unsigned, f);
  u = u + 0x7FFFu + ((u >> 16) & 1u);
  return (short)(u >> 16);
}
__device__ __forceinline__ float bf2f(short h){
  unsigned u = ((unsigned)(unsigned short)h) << 16;
  return __builtin_bit_cast(float, u);
}
__device__ __forceinline__ float sigm(float x){ return 1.f/(1.f + __expf(-x)); }
__device__ __forceinline__ float tanh_f(float x){ return 2.f/(1.f + __expf(-2.f*x)) - 1.f; }

// f32 -> OCP e4m3fn with RNE (for weight quantization in prep)
__device__ __forceinline__ unsigned char f2e4m3(float f){
  unsigned u = __builtin_bit_cast(unsigned, f);
  unsigned s = (u >> 24) & 0x80u;
  float af = fabsf(f);
  if (!(af < 448.f)) return (unsigned char)(s | 0x7E);
  if (af < 0.015625f){
    int q = (int)(af * 512.f + 0.5f);
    return (unsigned char)(s | (unsigned)q);
  }
  int e = (int)((u >> 23) & 0xff) - 127;
  unsigned m = u & 0x7fffffu;
  unsigned mant = m >> 20;
  unsigned rem = m & 0xfffffu;
  if (rem > 0x80000u || (rem == 0x80000u && (mant & 1u))) mant++;
  if (mant == 8u){ mant = 0u; e++; if (e > 8) return (unsigned char)(s | 0x7E); }
  return (unsigned char)(s | ((unsigned)(e + 7) << 3) | mant);
}

// HW packed f32->fp8 (e4m3fn on gfx950), byte0=a, byte1=b
__device__ __forceinline__ unsigned cvt2_fp8(float a, float b){
  unsigned r;
  asm volatile("v_cvt_pk_fp8_f32 %0, %1, %2" : "=v"(r) : "v"(a), "v"(b));
  return r;
}

// LDS-only barrier: waits LDS ops, leaves global loads/stores in flight
__device__ __forceinline__ void lds_barrier(){
  asm volatile("s_waitcnt lgkmcnt(0)" ::: "memory");
  __builtin_amdgcn_s_barrier();
  __builtin_amdgcn_sched_barrier(0);
}

// Opaque 8B global load: cannot be rematerialized/CSE'd -> stays register-resident.
__device__ __forceinline__ long gload8(const void* p){
  long r;
  asm volatile("global_load_dwordx2 %0, %1, off" : "=v"(r) : "v"(p));
  return r;
}

#define MFMA(a,b,c)  __builtin_amdgcn_mfma_f32_16x16x32_bf16((a),(b),(c),0,0,0)
#define MFMA8(a,b,c) __builtin_amdgcn_mfma_f32_16x16x32_fp8_fp8((a),(b),(c),0,0,0)

// ---------------- prep kernels ----------------

__global__ void prep_convw(const float* __restrict__ w, const float* __restrict__ cb,
                           const float* __restrict__ g, const float* __restrict__ bb,
                           const float* __restrict__ m, const float* __restrict__ v,
                           short* __restrict__ wT, float* __restrict__ bias,
                           int O, int I, int Cpad){
  int idx = blockIdx.x*blockDim.x + threadIdx.x;
  int total = 7*O*Cpad;
  if (idx < total){
    int kt = idx / (O*Cpad);
    int rem = idx - kt*O*Cpad;
    int n = rem / Cpad;
    int c = rem - n*Cpad;
    float s = g[n] * rsqrtf(v[n] + 1e-5f);
    float val = (c < I) ? w[((size_t)n*I + c)*7 + kt] * s : 0.f;
    wT[idx] = f2bf(val);
  }
  if (idx < O){
    float s = g[idx] * rsqrtf(v[idx] + 1e-5f);
    bias[idx] = (cb[idx] - m[idx]) * s + bb[idx];
  }
}

__global__ void cast_f32_bf16(const float* __restrict__ src, short* __restrict__ dst, int n){
  int i = blockIdx.x*blockDim.x + threadIdx.x;
  int stride = gridDim.x*blockDim.x;
  for (; i < n; i += stride) dst[i] = f2bf(src[i]);
}

__global__ void add_f32(const float* __restrict__ a, const float* __restrict__ b, float* __restrict__ c, int n){
  int i = blockIdx.x*blockDim.x + threadIdx.x;
  if (i < n) c[i] = a[i] + b[i];
}

// in [e][K][N] f32 -> out [e][N][K] bf16
__global__ void transp_k(const float* __restrict__ in, short* __restrict__ out, int E, int K, int N){
  int idx = blockIdx.x*blockDim.x + threadIdx.x;
  int total = E*K*N;
  if (idx >= total) return;
  int e = idx / (N*K);
  int rem = idx - e*N*K;
  int n = rem / K;
  int k = rem - n*K;
  out[idx] = f2bf(in[((size_t)e*K + k)*N + n]);
}

// quantize whh gate rows {i:0-255, g:512-767, o:768-1023} to fp8 e4m3, per-row scale.
// wq8: [3][256][256] bytes; inv_s: [3][256] floats (gate = inv_s * acc)
__global__ __launch_bounds__(64) void quant_whh(const float* __restrict__ whh,
                                                unsigned char* __restrict__ wq8,
                                                float* __restrict__ inv_s){
  const int rb = blockIdx.x;          // 0..767
  const int gsel = rb >> 8;           // 0=i, 1=g, 2=o
  const int r = rb & 255;
  const int srow = (gsel == 0 ? 0 : (gsel == 1 ? 512 : 768)) + r;
  const int lane = threadIdx.x;
  const float* wr = whh + (size_t)srow*256;
  float v4[4];
  float mx = 0.f;
#pragma unroll
  for (int j = 0; j < 4; ++j){ v4[j] = wr[lane*4 + j]; mx = fmaxf(mx, fabsf(v4[j])); }
#pragma unroll
  for (int off = 32; off >= 1; off >>= 1) mx = fmaxf(mx, __shfl_xor(mx, off));
  float s = (mx > 0.f) ? (448.f / mx) : 1.f;
  if (lane == 0) inv_s[gsel*256 + r] = (mx > 0.f) ? (mx / 448.f) : 0.f;
  unsigned w = 0;
#pragma unroll
  for (int j = 0; j < 4; ++j) w |= ((unsigned)f2e4m3(v4[j]*s)) << (8*j);
  *(unsigned*)(wq8 + ((size_t)(gsel*256 + r))*256 + lane*4) = w;
}

// ---------------- conv1: x(512,80,800)f32 -> a1[b][400][128] bf16 ----------------
#define C1_ROWS 86
#define C1_PITCH 104
__global__ __launch_bounds__(512) void conv1_k(const float* __restrict__ x, const short* __restrict__ wT,
                                               const float* __restrict__ bias, short* __restrict__ out){
  __shared__ short At[C1_ROWS*C1_PITCH];
  const int b = blockIdx.y;
  const int t0 = blockIdx.x * 80;
  const int tid = threadIdx.x;
  for (int i = tid; i < C1_ROWS*C1_PITCH; i += 512) At[i] = 0;
  __syncthreads();
  for (int idx = tid; idx < 80*C1_ROWS; idx += 512){
    int c = idx / C1_ROWS, i = idx - c*C1_ROWS;
    int t = t0 - 3 + i;
    float v = (t >= 0 && t < 800) ? x[((size_t)b*80 + c)*800 + t] : 0.f;
    At[i*C1_PITCH + c] = f2bf(v);
  }
  __syncthreads();
  const int lane = tid & 63, wave = tid >> 6;
  const int l15 = lane & 15, lq = lane >> 4;
  const int col = wave*16 + l15;
  f32x4 z = {0.f,0.f,0.f,0.f};
  f32x4 acc[5] = {z,z,z,z,z};
  for (int kt = 0; kt < 7; ++kt){
    for (int ks = 0; ks < 3; ++ks){
      bf16x8 bf = *(const bf16x8*)(wT + ((size_t)(kt*128 + col))*96 + ks*32 + lq*8);
#pragma unroll
      for (int mf = 0; mf < 5; ++mf){
        bf16x8 af = *(const bf16x8*)(At + (mf*16 + l15 + kt)*C1_PITCH + ks*32 + lq*8);
        acc[mf] = MFMA(af, bf, acc[mf]);
      }
    }
  }
  const float bs = bias[col];
#pragma unroll
  for (int mf = 0; mf < 5; ++mf){
    float v0 = fmaxf(acc[mf][0]+bs, 0.f), v1 = fmaxf(acc[mf][1]+bs, 0.f);
    float v2 = fmaxf(acc[mf][2]+bs, 0.f), v3 = fmaxf(acc[mf][3]+bs, 0.f);
    int tp = (t0 + mf*16 + lq*4) >> 1;
    out[((size_t)b*400 + tp  )*128 + col] = f2bf(fmaxf(v0,v1));
    out[((size_t)b*400 + tp+1)*128 + col] = f2bf(fmaxf(v2,v3));
  }
}

// ---------------- conv2: a1[b][400][128] -> a2[b][200][256] bf16 ----------------
#define C2_ROWS 86
#define C2_PITCH 136
__global__ __launch_bounds__(512) void conv2_k(const short* __restrict__ a1, const short* __restrict__ wT,
                                               const float* __restrict__ bias, short* __restrict__ out){
  __shared__ short At[C2_ROWS*C2_PITCH];
  const int b = blockIdx.y;
  const int t0 = blockIdx.x * 80;
  const int tid = threadIdx.x;
  bf16x8 zb = {0,0,0,0,0,0,0,0};
  for (int idx = tid; idx < C2_ROWS*16; idx += 512){
    int i = idx >> 4, c8 = idx & 15;
    int t = t0 - 3 + i;
    bf16x8 v = zb;
    if (t >= 0 && t < 400) v = *(const bf16x8*)(a1 + ((size_t)b*400 + t)*128 + c8*8);
    *(bf16x8*)(At + i*C2_PITCH + c8*8) = v;
  }
  __syncthreads();
  const int lane = tid & 63, wave = tid >> 6;
  const int l15 = lane & 15, lq = lane >> 4;
  f32x4 z = {0.f,0.f,0.f,0.f};
  f32x4 acc[5][2];
#pragma unroll
  for (int mf = 0; mf < 5; ++mf){ acc[mf][0] = z; acc[mf][1] = z; }
  for (int kt = 0; kt < 7; ++kt){
    for (int ks = 0; ks < 4; ++ks){
      bf16x8 bf0 = *(const bf16x8*)(wT + ((size_t)(kt*256 + wave*32      + l15))*128 + ks*32 + lq*8);
      bf16x8 bf1 = *(const bf16x8*)(wT + ((size_t)(kt*256 + wave*32 + 16 + l15))*128 + ks*32 + lq*8);
#pragma unroll
      for (int mf = 0; mf < 5; ++mf){
        bf16x8 af = *(const bf16x8*)(At + (mf*16 + l15 + kt)*C2_PITCH + ks*32 + lq*8);
        acc[mf][0] = MFMA(af, bf0, acc[mf][0]);
        acc[mf][1] = MFMA(af, bf1, acc[mf][1]);
      }
    }
  }
#pragma unroll
  for (int fi = 0; fi < 2; ++fi){
    int col = wave*32 + fi*16 + l15;
    float bs = bias[col];
#pragma unroll
    for (int mf = 0; mf < 5; ++mf){
      float v0 = fmaxf(acc[mf][fi][0]+bs, 0.f), v1 = fmaxf(acc[mf][fi][1]+bs, 0.f);
      float v2 = fmaxf(acc[mf][fi][2]+bs, 0.f), v3 = fmaxf(acc[mf][fi][3]+bs, 0.f);
      int tp = (t0 + mf*16 + lq*4) >> 1;
      out[((size_t)b*200 + tp  )*256 + col] = f2bf(fmaxf(v0,v1));
      out[((size_t)b*200 + tp+1)*256 + col] = f2bf(fmaxf(v2,v3));
    }
  }
}

// ---------------- xg GEMM -> permuted xgp layout (512-thread lstm) ----------------
// xgp (bf16): [gi][t][blk][tid512][8], elem = fi*4 + r
// One block stages the A-tile ONCE and loops gi=0..3 (was 4 blocks re-staging 4x).
__global__ __launch_bounds__(512) void xg_k(const short* __restrict__ A, const short* __restrict__ W,
                                            const float* __restrict__ bias, short* __restrict__ xg, int mode){
  __shared__ short At[128*264];
  const int M0 = blockIdx.x * 128;
  const int tid = threadIdx.x;
  const int t  = M0 >> 9;
  const int bl = M0 & 511;
  for (int idx = tid; idx < 128*32; idx += 512){
    int i = idx >> 5, c8 = idx & 31;
    int arow = (mode == 0) ? ((bl + i)*200 + t) : (M0 + i);
    *(bf16x8*)(At + i*264 + c8*8) = *(const bf16x8*)(A + (size_t)arow*256 + c8*8);
  }
  __syncthreads();
  const int lane = tid & 63, wave = tid >> 6, l15 = lane & 15, lq = lane >> 4;
  const int blkbase = bl >> 4;
  for (int gi = 0; gi < 4; ++gi){
    const int N0 = gi * 256;
    f32x4 z = {0.f,0.f,0.f,0.f};
    f32x4 acc[8][2];
#pragma unroll
    for (int mf = 0; mf < 8; ++mf){ acc[mf][0] = z; acc[mf][1] = z; }
    for (int ks = 0; ks < 8; ++ks){
      bf16x8 bf0 = *(const bf16x8*)(W + ((size_t)(N0 + wave*32      + l15))*256 + ks*32 + lq*8);
      bf16x8 bf1 = *(const bf16x8*)(W + ((size_t)(N0 + wave*32 + 16 + l15))*256 + ks*32 + lq*8);
#pragma unroll
      for (int mf = 0; mf < 8; ++mf){
        bf16x8 af = *(const bf16x8*)(At + (mf*16 + l15)*264 + ks*32 + lq*8);
        acc[mf][0] = MFMA(af, bf0, acc[mf][0]);
        acc[mf][1] = MFMA(af, bf1, acc[mf][1]);
      }
    }
    const float bs0 = bias[N0 + wave*32 + l15];
    const float bs1 = bias[N0 + wave*32 + 16 + l15];
#pragma unroll
    for (int mf = 0; mf < 8; ++mf){
      bf16x8 vch;
#pragma unroll
      for (int r = 0; r < 4; ++r){
        vch[r]     = f2bf(acc[mf][0][r] + bs0);
        vch[4 + r] = f2bf(acc[mf][1][r] + bs1);
      }
      size_t chunk = (((size_t)gi*200 + t)*32 + blkbase + mf)*512 + wave*64 + lq*16 + l15;
      *(bf16x8*)(xg + chunk*8) = vch;
    }
  }
}

// ---------------- LSTM recurrence (r7 structure): fp8 i/g LDS, fp8 o regs, f bf16 L2-streamed ----------------
// 512 threads, 8 waves x 32 cols. h kept in bf16 + fp8 LDS double-buffers. 1 barrier/step.
__global__ __launch_bounds__(512)
void lstm_k(const short* __restrict__ xgp, const short* __restrict__ whhb,
            const unsigned char* __restrict__ wq8, const float* __restrict__ inv_s,
            short* __restrict__ hseq, float* __restrict__ feat, int mode){
  __shared__ __align__(16) unsigned char wq[2*256*256];   // i, g (XOR-swizzled rows)
  __shared__ __align__(16) unsigned char h8l[2][16*264];  // fp8 h
  __shared__ __align__(16) short hbl[2][16*264];          // bf16 h
  const int blk = blockIdx.x;
  const int b0 = blk * 16;
  const int tid = threadIdx.x, lane = tid & 63, wave = tid >> 6;
  const int l15 = lane & 15, lq = lane >> 4;
  const int j0 = wave * 32;
  const int swz = (l15 & 7) << 4;

  for (int i = tid; i < 16*264; i += 512){ h8l[0][i] = 0; hbl[0][i] = 0; }
  // stage i,g fp8 weights into LDS (swizzled)
  for (int idx = tid; idx < 2*256*16; idx += 512){
    int gg = idx >> 12;
    int rem = idx & 4095;
    int row = rem >> 4, c16 = (rem & 15) << 4;
    uint4 v = *(const uint4*)(wq8 + ((size_t)(gg*256 + row))*256 + c16);
    *(uint4*)(&wq[gg*65536 + row*256 + (c16 ^ ((row & 7) << 4))]) = v;
  }
  // o-gate fp8 fragments pinned in registers: 16 x 8B = 32 VGPRs
  long oreg[2][8];
#pragma unroll
  for (int fi = 0; fi < 2; ++fi)
#pragma unroll
    for (int kk = 0; kk < 8; ++kk)
      oreg[fi][kk] = gload8(wq8 + ((size_t)(2*256 + j0 + fi*16 + l15))*256 + kk*32 + lq*8);
  // dequant scales
  float is_i[2], is_g[2], is_o[2];
#pragma unroll
  for (int fi = 0; fi < 2; ++fi){
    int col = j0 + fi*16 + l15;
    is_i[fi] = inv_s[col];
    is_g[fi] = inv_s[256 + col];
    is_o[fi] = inv_s[512 + col];
  }
  asm volatile("s_waitcnt vmcnt(0)" ::: "memory");

  float c[2][4];
#pragma unroll
  for (int fi=0; fi<2; ++fi)
#pragma unroll
    for (int r=0; r<4; ++r) c[fi][r] = 0.f;

  __syncthreads();

  const size_t GI = (size_t)200*32*512*8;  // per-gi stride in shorts
  bf16x8 xq0, xq1, xq2, xq3;
  {
    const short* p = xgp + (((size_t)0*32 + blk)*512 + tid)*8;
    xq0 = *(const bf16x8*)(p);
    xq1 = *(const bf16x8*)(p + GI);
    xq2 = *(const bf16x8*)(p + 2*GI);
    xq3 = *(const bf16x8*)(p + 3*GI);
  }

  const short* fbase = whhb + (size_t)256*256;  // f-gate rows, bf16
  int cur = 0;

  for (int t = 0; t < 200; ++t){
    const unsigned char* h8c = h8l[cur];
    const short* hbc = hbl[cur];
    f32x4 zz = {0.f,0.f,0.f,0.f};
    f32x4 acc[4][2];
#pragma unroll
    for (int gi=0; gi<4; ++gi){ acc[gi][0] = zz; acc[gi][1] = zz; }
#pragma unroll
    for (int kk = 0; kk < 8; ++kk){
      bf16x8 wf0 = *(const bf16x8*)(fbase + ((size_t)(j0      + l15))*256 + kk*32 + lq*8);
      bf16x8 wf1 = *(const bf16x8*)(fbase + ((size_t)(j0 + 16 + l15))*256 + kk*32 + lq*8);
      bf16x8 avb = *(const bf16x8*)(hbc + l15*264 + kk*32 + lq*8);
      long av8 = *(const long*)(h8c + l15*264 + kk*32 + lq*8);
      int bo = (kk*32 + lq*8) ^ swz;
      long wi0 = *(const long*)(&wq[          (j0      + l15)*256 + bo]);
      long wi1 = *(const long*)(&wq[          (j0 + 16 + l15)*256 + bo]);
      long wg0 = *(const long*)(&wq[65536 +   (j0      + l15)*256 + bo]);
      long wg1 = *(const long*)(&wq[65536 +   (j0 + 16 + l15)*256 + bo]);
      acc[0][0] = MFMA8(av8, wi0, acc[0][0]);
      acc[0][1] = MFMA8(av8, wi1, acc[0][1]);
      acc[1][0] = MFMA (avb, wf0, acc[1][0]);
      acc[1][1] = MFMA (avb, wf1, acc[1][1]);
      acc[2][0] = MFMA8(av8, wg0, acc[2][0]);
      acc[2][1] = MFMA8(av8, wg1, acc[2][1]);
      acc[3][0] = MFMA8(av8, oreg[0][kk], acc[3][0]);
      acc[3][1] = MFMA8(av8, oreg[1][kk], acc[3][1]);
    }
    short hnew[2][4];
    float hfv[2][4];
#pragma unroll
    for (int fi=0; fi<2; ++fi){
#pragma unroll
      for (int r=0; r<4; ++r){
        int e = fi*4 + r;
        float iv = acc[0][fi][r]*is_i[fi] + bf2f(xq0[e]);
        float fv = acc[1][fi][r]          + bf2f(xq1[e]);
        float gv = acc[2][fi][r]*is_g[fi] + bf2f(xq2[e]);
        float ov = acc[3][fi][r]*is_o[fi] + bf2f(xq3[e]);
        float cs = sigm(fv)*c[fi][r] + sigm(iv)*tanh_f(gv);
        c[fi][r] = cs;
        float hv = sigm(ov)*tanh_f(cs);
        hfv[fi][r] = hv;
        hnew[fi][r] = f2bf(hv);
      }
    }
    if (t + 1 < 200){
      const short* p = xgp + (((size_t)(t+1)*32 + blk)*512 + tid)*8;
      xq0 = *(const bf16x8*)(p);
      xq1 = *(const bf16x8*)(p + GI);
      xq2 = *(const bf16x8*)(p + 2*GI);
      xq3 = *(const bf16x8*)(p + 3*GI);
    }
    // write new h (bf16 + fp8) into the other buffers
    short* hbn = hbl[cur ^ 1];
    unsigned char* h8n = h8l[cur ^ 1];
#pragma unroll
    for (int fi=0; fi<2; ++fi){
      int col = j0 + fi*16 + l15;
      unsigned p01 = cvt2_fp8(hfv[fi][0], hfv[fi][1]);
      unsigned p23 = cvt2_fp8(hfv[fi][2], hfv[fi][3]);
      h8n[(lq*4+0)*264 + col] = (unsigned char)(p01 & 0xff);
      h8n[(lq*4+1)*264 + col] = (unsigned char)((p01 >> 8) & 0xff);
      h8n[(lq*4+2)*264 + col] = (unsigned char)(p23 & 0xff);
      h8n[(lq*4+3)*264 + col] = (unsigned char)((p23 >> 8) & 0xff);
#pragma unroll
      for (int r=0; r<4; ++r)
        hbn[(lq*4+r)*264 + col] = hnew[fi][r];
    }
    if (mode == 0){
      short* hs = hseq + ((size_t)t*512 + b0)*256;
#pragma unroll
      for (int fi=0; fi<2; ++fi)
#pragma unroll
        for (int r=0; r<4; ++r)
          hs[(lq*4+r)*256 + j0 + fi*16 + l15] = hnew[fi][r];
    } else if (t == 199){
#pragma unroll
      for (int fi=0; fi<2; ++fi)
#pragma unroll
        for (int r=0; r<4; ++r)
          feat[(size_t)(b0 + lq*4 + r)*256 + j0 + fi*16 + l15] = bf2f(hnew[fi][r]);
    }
    lds_barrier();
    cur ^= 1;
  }
}

// ---------------- gating + feat cast ----------------
__global__ __launch_bounds__(64) void gating_k(const float* __restrict__ feat, const float* __restrict__ gw,
    const float* __restrict__ gb, const float* __restrict__ bg, const float* __restrict__ bb,
    const float* __restrict__ bm, const float* __restrict__ bv,
    float* __restrict__ gating, short* __restrict__ featb){
  const int b = blockIdx.x, lane = threadIdx.x;
  __shared__ float fr[256];
  __shared__ float lg[12];
  for (int i = lane; i < 256; i += 64){
    float v = feat[(size_t)b*256 + i];
    fr[i] = v;
    featb[(size_t)b*256 + i] = f2bf(v);
  }
  __syncthreads();
  if (lane < 12){
    float s = gb[lane];
    for (int k = 0; k < 256; ++k) s += fr[k]*gw[lane*256 + k];
    s = (s - bm[lane])*rsqrtf(bv[lane] + 1e-5f)*bg[lane] + bb[lane];
    lg[lane] = s;
  }
  __syncthreads();
  if (lane == 0){
    float mx = lg[0];
    for (int g = 1; g < 12; ++g) mx = fmaxf(mx, lg[g]);
    float den = 0.f, ex[12];
    for (int g = 0; g < 12; ++g){ ex[g] = __expf(lg[g]-mx); den += ex[g]; }
    for (int g = 0; g < 12; ++g) gating[b*12 + g] = ex[g]/den;
  }
}

// ---------------- MoE experts (atomic accumulate into moe) ----------------
__global__ __launch_bounds__(256) void moe_k(const short* __restrict__ featb, const short* __restrict__ w1t,
    const float* __restrict__ b1, const short* __restrict__ w2t, const float* __restrict__ b2,
    const float* __restrict__ gating, float* __restrict__ moe){
  __shared__ short eh[32*520];
  const int e = blockIdx.x;
  const int b0 = blockIdx.y * 32;
  const int tid = threadIdx.x, lane = tid & 63, wave = tid >> 6;
  const int l15 = lane & 15, lq = lane >> 4;
  f32x4 z = {0.f,0.f,0.f,0.f};
  f32x4 acc[2][8];
#pragma unroll
  for (int nf = 0; nf < 8; ++nf){ acc[0][nf] = z; acc[1][nf] = z; }
  for (int ks = 0; ks < 8; ++ks){
    bf16x8 af0 = *(const bf16x8*)(featb + ((size_t)(b0      + l15))*256 + ks*32 + lq*8);
    bf16x8 af1 = *(const bf16x8*)(featb + ((size_t)(b0 + 16 + l15))*256 + ks*32 + lq*8);
#pragma unroll
    for (int nf = 0; nf < 8; ++nf){
      bf16x8 bf = *(const bf16x8*)(w1t + ((size_t)(e*512 + wave*128 + nf*16 + l15))*256 + ks*32 + lq*8);
      acc[0][nf] = MFMA(af0, bf, acc[0][nf]);
      acc[1][nf] = MFMA(af1, bf, acc[1][nf]);
    }
  }
#pragma unroll
  for (int mf = 0; mf < 2; ++mf){
#pragma unroll
    for (int nf = 0; nf < 8; ++nf){
      int h = wave*128 + nf*16 + l15;
      float bb = b1[e*512 + h];
#pragma unroll
      for (int r = 0; r < 4; ++r){
        float v = acc[mf][nf][r] + bb;
        v = 0.5f*v*(1.f + erff(v*0.70710678118f));
        eh[(mf*16 + lq*4 + r)*520 + h] = f2bf(v);
      }
    }
  }
  __syncthreads();
  f32x4 a2c[2][4];
#pragma unroll
  for (int nf = 0; nf < 4; ++nf){ a2c[0][nf] = z; a2c[1][nf] = z; }
  for (int ks = 0; ks < 16; ++ks){
    bf16x8 af0 = *(const bf16x8*)(eh + (l15     )*520 + ks*32 + lq*8);
    bf16x8 af1 = *(const bf16x8*)(eh + (16 + l15)*520 + ks*32 + lq*8);
#pragma unroll
    for (int nf = 0; nf < 4; ++nf){
      bf16x8 bf = *(const bf16x8*)(w2t + ((size_t)(e*256 + wave*64 + nf*16 + l15))*512 + ks*32 + lq*8);
      a2c[0][nf] = MFMA(af0, bf, a2c[0][nf]);
      a2c[1][nf] = MFMA(af1, bf, a2c[1][nf]);
    }
  }
#pragma unroll
  for (int mf = 0; mf < 2; ++mf){
#pragma unroll
    for (int r = 0; r < 4; ++r){
      int b = b0 + mf*16 + lq*4 + r;
      float ge = gating[b*12 + e];
#pragma unroll
      for (int nf = 0; nf < 4; ++nf){
        int d = wave*64 + nf*16 + l15;
        atomicAdd(&moe[(size_t)b*256 + d], ge*(a2c[mf][nf][r] + b2[e*256 + d]));
      }
    }
  }
}

// ---------------- towers + head + sigmoid ----------------
__global__ __launch_bounds__(256) void tower_k(const float* __restrict__ moe,
    const float* f1sw, const float* f1sb, const float* f2sw, const float* f2sb,
    const float* f3sw, const float* f3sb,
    const float* f1pw, const float* f1pb, const float* f2pw, const float* f2pb,
    const float* f3pw, const float* f3pb,
    const float* hw, const float* hb, float* __restrict__ out){
  __shared__ float mt[16*256];
  __shared__ float h1[2][16][128];
  __shared__ float h2[2][16][64];
  __shared__ float h3[2][16];
  __shared__ float gl[16][2];
  const int b0 = blockIdx.x * 16;
  const int tid = threadIdx.x;
  for (int i = tid; i < 16*256; i += 256) mt[i] = moe[(size_t)b0*256 + i];
  __syncthreads();
  for (int idx = tid; idx < 4096; idx += 256){
    int tower = idx >> 11, b = (idx >> 7) & 15, n = idx & 127;
    const float* w = tower ? f1pw : f1sw;
    float s = (tower ? f1pb : f1sb)[n];
    for (int k = 0; k < 256; ++k) s += mt[b*256 + k]*w[n*256 + k];
    h1[tower][b][n] = fmaxf(s, 0.f);
  }
  __syncthreads();
  for (int idx = tid; idx < 2048; idx += 256){
    int tower = idx >> 10, b = (idx >> 6) & 15, n = idx & 63;
    const float* w = tower ? f2pw : f2sw;
    float s = (tower ? f2pb : f2sb)[n];
    for (int k = 0; k < 128; ++k) s += h1[tower][b][k]*w[n*128 + k];
    h2[tower][b][n] = fmaxf(s, 0.f);
  }
  __syncthreads();
  if (tid < 32){
    int tower = tid >> 4, b = tid & 15;
    const float* w = tower ? f3pw : f3sw;
    float s = (tower ? f3pb : f3sb)[0];
    for (int k = 0; k < 64; ++k) s += h2[tower][b][k]*w[k];
    h3[tower][b] = s;
  } else if (tid < 64){
    int i2 = tid - 32; int b = i2 >> 1, g = i2 & 1;
    float s = hb[g];
    for (int k = 0; k < 256; ++k) s += mt[b*256 + k]*hw[g*256 + k];
    gl[b][g] = s;
  }
  __syncthreads();
  if (tid < 16){
    int b = tid;
    float g0 = 1.f/(1.f + __expf(gl[b][1] - gl[b][0]));
    float val = g0*h3[0][b] + (1.f - g0)*h3[1][b];
    out[b0 + b] = 1.f/(1.f + __expf(-val));
  }
}

// ---------------- host ----------------
extern "C" void kernel_launch(void* const* d_in, const int* in_sizes, int n_in,
                              void* d_out, int out_size, void* d_ws, size_t ws_size,
                              hipStream_t stream){
  (void)in_sizes; (void)n_in; (void)out_size; (void)ws_size;
  const float* x       = (const float*)d_in[0];
  const float* conv1_w = (const float*)d_in[1];
  const float* conv1_b = (const float*)d_in[2];
  const float* bn1_g   = (const float*)d_in[3];
  const float* bn1_b   = (const float*)d_in[4];
  const float* bn1_m   = (const float*)d_in[5];
  const float* bn1_v   = (const float*)d_in[6];
  const float* conv2_w = (const float*)d_in[7];
  const float* conv2_b = (const float*)d_in[8];
  const float* bn2_g   = (const float*)d_in[9];
  const float* bn2_b   = (const float*)d_in[10];
  const float* bn2_m   = (const float*)d_in[11];
  const float* bn2_v   = (const float*)d_in[12];
  const float* wih0    = (const float*)d_in[13];
  const float* whh0    = (const float*)d_in[14];
  const float* bih0    = (const float*)d_in[15];
  const float* bhh0    = (const float*)d_in[16];
  const float* wih1    = (const float*)d_in[17];
  const float* whh1    = (const float*)d_in[18];
  const float* bih1    = (const float*)d_in[19];
  const float* bhh1    = (const float*)d_in[20];
  const float* gate_w  = (const float*)d_in[21];
  const float* gate_b  = (const float*)d_in[22];
  const float* gbn_g   = (const float*)d_in[23];
  const float* gbn_b   = (const float*)d_in[24];
  const float* gbn_m   = (const float*)d_in[25];
  const float* gbn_v   = (const float*)d_in[26];
  const float* exp_w1  = (const float*)d_in[27];
  const float* exp_b1  = (const float*)d_in[28];
  const float* exp_w2  = (const float*)d_in[29];
  const float* exp_b2  = (const float*)d_in[30];
  const float* fc1s_w  = (const float*)d_in[31];
  const float* fc1s_b  = (const float*)d_in[32];
  const float* fc2s_w  = (const float*)d_in[33];
  const float* fc2s_b  = (const float*)d_in[34];
  const float* fc3s_w  = (const float*)d_in[35];
  const float* fc3s_b  = (const float*)d_in[36];
  const float* fc1p_w  = (const float*)d_in[37];
  const float* fc1p_b  = (const float*)d_in[38];
  const float* fc2p_w  = (const float*)d_in[39];
  const float* fc2p_b  = (const float*)d_in[40];
  const float* fc3p_w  = (const float*)d_in[41];
  const float* fc3p_b  = (const float*)d_in[42];
  const float* head_w  = (const float*)d_in[43];
  const float* head_b  = (const float*)d_in[44];
  float* out = (float*)d_out;

  char* base = (char*)d_ws;
  size_t off = 0;
  auto alloc = [&](size_t nbytes)->void*{
    off = (off + 255) & ~(size_t)255;
    void* p = base + off;
    off += nbytes;
    return p;
  };
  short* w1T    = (short*)alloc((size_t)7*128*96*2);
  float* b1c    = (float*)alloc(128*4);
  short* w2T    = (short*)alloc((size_t)7*256*128*2);
  float* b2c    = (float*)alloc(256*4);
  short* wih0b  = (short*)alloc((size_t)1024*256*2);
  short* whh0b  = (short*)alloc((size_t)1024*256*2);
  short* wih1b  = (short*)alloc((size_t)1024*256*2);
  short* whh1b  = (short*)alloc((size_t)1024*256*2);
  float* bias0  = (float*)alloc(1024*4);
  float* bias1  = (float*)alloc(1024*4);
  unsigned char* wq8_0 = (unsigned char*)alloc((size_t)3*256*256);
  unsigned char* wq8_1 = (unsigned char*)alloc((size_t)3*256*256);
  float* invs0  = (float*)alloc(3*256*4);
  float* invs1  = (float*)alloc(3*256*4);
  short* eW1T   = (short*)alloc((size_t)12*512*256*2);
  short* eW2T   = (short*)alloc((size_t)12*256*512*2);
  short* featb  = (short*)alloc((size_t)512*256*2);
  float* gatingb= (float*)alloc((size_t)512*12*4);
  float* moebuf = (float*)alloc((size_t)512*256*4);
  float* featf  = (float*)alloc((size_t)512*256*4);
  short* a1     = (short*)alloc((size_t)512*400*128*2);
  short* a2     = (short*)alloc((size_t)512*200*256*2);
  short* xgbuf  = (short*)alloc((size_t)200*512*1024*2);
  short* h0seq  = a1;  // a1 dead after conv2

  // prep
  prep_convw<<<(7*128*96 + 255)/256, 256, 0, stream>>>(conv1_w, conv1_b, bn1_g, bn1_b, bn1_m, bn1_v, w1T, b1c, 128, 80, 96);
  prep_convw<<<(7*256*128 + 255)/256, 256, 0, stream>>>(conv2_w, conv2_b, bn2_g, bn2_b, bn2_m, bn2_v, w2T, b2c, 256, 128, 128);
  cast_f32_bf16<<<512, 256, 0, stream>>>(wih0, wih0b, 1024*256);
  cast_f32_bf16<<<512, 256, 0, stream>>>(whh0, whh0b, 1024*256);
  cast_f32_bf16<<<512, 256, 0, stream>>>(wih1, wih1b, 1024*256);
  cast_f32_bf16<<<512, 256, 0, stream>>>(whh1, whh1b, 1024*256);
  quant_whh<<<768, 64, 0, stream>>>(whh0, wq8_0, invs0);
  quant_whh<<<768, 64, 0, stream>>>(whh1, wq8_1, invs1);
  add_f32<<<4, 256, 0, stream>>>(bih0, bhh0, bias0, 1024);
  add_f32<<<4, 256, 0, stream>>>(bih1, bhh1, bias1, 1024);
  transp_k<<<(12*512*256 + 255)/256, 256, 0, stream>>>(exp_w1, eW1T, 12, 256, 512);
  transp_k<<<(12*256*512 + 255)/256, 256, 0, stream>>>(exp_w2, eW2T, 12, 512, 256);

  // pipeline
  conv1_k<<<dim3(10, 512), 512, 0, stream>>>(x, w1T, b1c, a1);
  conv2_k<<<dim3(5, 512), 512, 0, stream>>>(a1, w2T, b2c, a2);
  xg_k<<<800, 512, 0, stream>>>(a2, wih0b, bias0, xgbuf, 0);
  lstm_k<<<32, 512, 0, stream>>>(xgbuf, whh0b, wq8_0, invs0, h0seq, nullptr, 0);
  xg_k<<<800, 512, 0, stream>>>(h0seq, wih1b, bias1, xgbuf, 1);
  lstm_k<<<32, 512, 0, stream>>>(xgbuf, whh1b, wq8_1, invs1, nullptr, featf, 1);
  gating_k<<<512, 64, 0, stream>>>(featf, gate_w, gate_b, gbn_g, gbn_b, gbn_m, gbn_v, gatingb, featb);
  hipMemsetAsync(moebuf, 0, (size_t)512*256*4, stream);
  moe_k<<<dim3(12, 16), 256, 0, stream>>>(featb, eW1T, exp_b1, eW2T, exp_b2, gatingb, moebuf);
  tower_k<<<32, 256, 0, stream>>>(moebuf,
      fc1s_w, fc1s_b, fc2s_w, fc2s_b, fc3s_w, fc3s_b,
      fc1p_w, fc1p_b, fc2p_w, fc2p_b, fc3p_w, fc3p_b,
      head_w, head_b, out);
}

// Round 10
// 2058.235 us; speedup vs baseline: 1.4506x; 1.2406x over previous
//
#include <hip/hip_runtime.h>
#include <hip/hip_bf16.h>
#include <math.h>

typedef short bf16x8 __attribute__((ext_vector_type(8)));
typedef float f32x4  __attribute__((ext_vector_type(4)));

__device__ __forceinline__ short f2bf(float f){
  unsigned u = __builtin_bit_cast(unsigned, f);
  u = u + 0x7FFFu + ((u >> 16) & 1u);
  return (short)(u >> 16);
}
__device__ __forceinline__ float bf2f(short h){
  unsigned u = ((unsigned)(unsigned short)h) << 16;
  return __builtin_bit_cast(float, u);
}
// single-instruction v_rcp_f32 (~1ulp) instead of the ~7-inst exact-div sequence
__device__ __forceinline__ float sigm(float x){
  return __builtin_amdgcn_rcpf(1.f + __expf(-x));
}
__device__ __forceinline__ float tanh_f(float x){
  float e = __expf(-2.f*x);
  return (1.f - e) * __builtin_amdgcn_rcpf(1.f + e);
}

// f32 -> OCP e4m3fn with RNE (for weight quantization in prep)
__device__ __forceinline__ unsigned char f2e4m3(float f){
  unsigned u = __builtin_bit_cast(unsigned, f);
  unsigned s = (u >> 24) & 0x80u;
  float af = fabsf(f);
  if (!(af < 448.f)) return (unsigned char)(s | 0x7E);
  if (af < 0.015625f){
    int q = (int)(af * 512.f + 0.5f);
    return (unsigned char)(s | (unsigned)q);
  }
  int e = (int)((u >> 23) & 0xff) - 127;
  unsigned m = u & 0x7fffffu;
  unsigned mant = m >> 20;
  unsigned rem = m & 0xfffffu;
  if (rem > 0x80000u || (rem == 0x80000u && (mant & 1u))) mant++;
  if (mant == 8u){ mant = 0u; e++; if (e > 8) return (unsigned char)(s | 0x7E); }
  return (unsigned char)(s | ((unsigned)(e + 7) << 3) | mant);
}

// HW packed f32->fp8 (e4m3fn on gfx950), byte0=a, byte1=b
__device__ __forceinline__ unsigned cvt2_fp8(float a, float b){
  unsigned r;
  asm volatile("v_cvt_pk_fp8_f32 %0, %1, %2" : "=v"(r) : "v"(a), "v"(b));
  return r;
}

// LDS-only barrier: waits LDS ops, leaves global loads/stores in flight
__device__ __forceinline__ void lds_barrier(){
  asm volatile("s_waitcnt lgkmcnt(0)" ::: "memory");
  __builtin_amdgcn_s_barrier();
  __builtin_amdgcn_sched_barrier(0);
}

// Opaque 8B global load: cannot be rematerialized/CSE'd -> stays register-resident.
__device__ __forceinline__ long gload8(const void* p){
  long r;
  asm volatile("global_load_dwordx2 %0, %1, off" : "=v"(r) : "v"(p));
  return r;
}

#define MFMA(a,b,c)  __builtin_amdgcn_mfma_f32_16x16x32_bf16((a),(b),(c),0,0,0)
#define MFMA8(a,b,c) __builtin_amdgcn_mfma_f32_16x16x32_fp8_fp8((a),(b),(c),0,0,0)

// ---------------- prep kernels ----------------

__global__ void prep_convw(const float* __restrict__ w, const float* __restrict__ cb,
                           const float* __restrict__ g, const float* __restrict__ bb,
                           const float* __restrict__ m, const float* __restrict__ v,
                           short* __restrict__ wT, float* __restrict__ bias,
                           int O, int I, int Cpad){
  int idx = blockIdx.x*blockDim.x + threadIdx.x;
  int total = 7*O*Cpad;
  if (idx < total){
    int kt = idx / (O*Cpad);
    int rem = idx - kt*O*Cpad;
    int n = rem / Cpad;
    int c = rem - n*Cpad;
    float s = g[n] * rsqrtf(v[n] + 1e-5f);
    float val = (c < I) ? w[((size_t)n*I + c)*7 + kt] * s : 0.f;
    wT[idx] = f2bf(val);
  }
  if (idx < O){
    float s = g[idx] * rsqrtf(v[idx] + 1e-5f);
    bias[idx] = (cb[idx] - m[idx]) * s + bb[idx];
  }
}

__global__ void cast_f32_bf16(const float* __restrict__ src, short* __restrict__ dst, int n){
  int i = blockIdx.x*blockDim.x + threadIdx.x;
  int stride = gridDim.x*blockDim.x;
  for (; i < n; i += stride) dst[i] = f2bf(src[i]);
}

__global__ void add_f32(const float* __restrict__ a, const float* __restrict__ b, float* __restrict__ c, int n){
  int i = blockIdx.x*blockDim.x + threadIdx.x;
  if (i < n) c[i] = a[i] + b[i];
}

// in [e][K][N] f32 -> out [e][N][K] bf16
__global__ void transp_k(const float* __restrict__ in, short* __restrict__ out, int E, int K, int N){
  int idx = blockIdx.x*blockDim.x + threadIdx.x;
  int total = E*K*N;
  if (idx >= total) return;
  int e = idx / (N*K);
  int rem = idx - e*N*K;
  int n = rem / K;
  int k = rem - n*K;
  out[idx] = f2bf(in[((size_t)e*K + k)*N + n]);
}

// quantize whh gate rows {i:0-255, g:512-767, o:768-1023} to fp8 e4m3, per-row scale.
// wq8: [3][256][256] bytes; inv_s: [3][256] floats (gate = inv_s * acc)
__global__ __launch_bounds__(64) void quant_whh(const float* __restrict__ whh,
                                                unsigned char* __restrict__ wq8,
                                                float* __restrict__ inv_s){
  const int rb = blockIdx.x;          // 0..767
  const int gsel = rb >> 8;           // 0=i, 1=g, 2=o
  const int r = rb & 255;
  const int srow = (gsel == 0 ? 0 : (gsel == 1 ? 512 : 768)) + r;
  const int lane = threadIdx.x;
  const float* wr = whh + (size_t)srow*256;
  float v4[4];
  float mx = 0.f;
#pragma unroll
  for (int j = 0; j < 4; ++j){ v4[j] = wr[lane*4 + j]; mx = fmaxf(mx, fabsf(v4[j])); }
#pragma unroll
  for (int off = 32; off >= 1; off >>= 1) mx = fmaxf(mx, __shfl_xor(mx, off));
  float s = (mx > 0.f) ? (448.f / mx) : 1.f;
  if (lane == 0) inv_s[gsel*256 + r] = (mx > 0.f) ? (mx / 448.f) : 0.f;
  unsigned w = 0;
#pragma unroll
  for (int j = 0; j < 4; ++j) w |= ((unsigned)f2e4m3(v4[j]*s)) << (8*j);
  *(unsigned*)(wq8 + ((size_t)(gsel*256 + r))*256 + lane*4) = w;
}

// ---------------- conv1: x(512,80,800)f32 -> a1[b][400][128] bf16 ----------------
#define C1_ROWS 86
#define C1_PITCH 104
__global__ __launch_bounds__(512) void conv1_k(const float* __restrict__ x, const short* __restrict__ wT,
                                               const float* __restrict__ bias, short* __restrict__ out){
  __shared__ short At[C1_ROWS*C1_PITCH];
  const int b = blockIdx.y;
  const int t0 = blockIdx.x * 80;
  const int tid = threadIdx.x;
  for (int i = tid; i < C1_ROWS*C1_PITCH; i += 512) At[i] = 0;
  __syncthreads();
  for (int idx = tid; idx < 80*C1_ROWS; idx += 512){
    int c = idx / C1_ROWS, i = idx - c*C1_ROWS;
    int t = t0 - 3 + i;
    float v = (t >= 0 && t < 800) ? x[((size_t)b*80 + c)*800 + t] : 0.f;
    At[i*C1_PITCH + c] = f2bf(v);
  }
  __syncthreads();
  const int lane = tid & 63, wave = tid >> 6;
  const int l15 = lane & 15, lq = lane >> 4;
  const int col = wave*16 + l15;
  f32x4 z = {0.f,0.f,0.f,0.f};
  f32x4 acc[5] = {z,z,z,z,z};
  for (int kt = 0; kt < 7; ++kt){
    for (int ks = 0; ks < 3; ++ks){
      bf16x8 bf = *(const bf16x8*)(wT + ((size_t)(kt*128 + col))*96 + ks*32 + lq*8);
#pragma unroll
      for (int mf = 0; mf < 5; ++mf){
        bf16x8 af = *(const bf16x8*)(At + (mf*16 + l15 + kt)*C1_PITCH + ks*32 + lq*8);
        acc[mf] = MFMA(af, bf, acc[mf]);
      }
    }
  }
  const float bs = bias[col];
#pragma unroll
  for (int mf = 0; mf < 5; ++mf){
    float v0 = fmaxf(acc[mf][0]+bs, 0.f), v1 = fmaxf(acc[mf][1]+bs, 0.f);
    float v2 = fmaxf(acc[mf][2]+bs, 0.f), v3 = fmaxf(acc[mf][3]+bs, 0.f);
    int tp = (t0 + mf*16 + lq*4) >> 1;
    out[((size_t)b*400 + tp  )*128 + col] = f2bf(fmaxf(v0,v1));
    out[((size_t)b*400 + tp+1)*128 + col] = f2bf(fmaxf(v2,v3));
  }
}

// ---------------- conv2: a1[b][400][128] -> a2[b][200][256] bf16 ----------------
#define C2_ROWS 86
#define C2_PITCH 136
__global__ __launch_bounds__(512) void conv2_k(const short* __restrict__ a1, const short* __restrict__ wT,
                                               const float* __restrict__ bias, short* __restrict__ out){
  __shared__ short At[C2_ROWS*C2_PITCH];
  const int b = blockIdx.y;
  const int t0 = blockIdx.x * 80;
  const int tid = threadIdx.x;
  bf16x8 zb = {0,0,0,0,0,0,0,0};
  for (int idx = tid; idx < C2_ROWS*16; idx += 512){
    int i = idx >> 4, c8 = idx & 15;
    int t = t0 - 3 + i;
    bf16x8 v = zb;
    if (t >= 0 && t < 400) v = *(const bf16x8*)(a1 + ((size_t)b*400 + t)*128 + c8*8);
    *(bf16x8*)(At + i*C2_PITCH + c8*8) = v;
  }
  __syncthreads();
  const int lane = tid & 63, wave = tid >> 6;
  const int l15 = lane & 15, lq = lane >> 4;
  f32x4 z = {0.f,0.f,0.f,0.f};
  f32x4 acc[5][2];
#pragma unroll
  for (int mf = 0; mf < 5; ++mf){ acc[mf][0] = z; acc[mf][1] = z; }
  for (int kt = 0; kt < 7; ++kt){
    for (int ks = 0; ks < 4; ++ks){
      bf16x8 bf0 = *(const bf16x8*)(wT + ((size_t)(kt*256 + wave*32      + l15))*128 + ks*32 + lq*8);
      bf16x8 bf1 = *(const bf16x8*)(wT + ((size_t)(kt*256 + wave*32 + 16 + l15))*128 + ks*32 + lq*8);
#pragma unroll
      for (int mf = 0; mf < 5; ++mf){
        bf16x8 af = *(const bf16x8*)(At + (mf*16 + l15 + kt)*C2_PITCH + ks*32 + lq*8);
        acc[mf][0] = MFMA(af, bf0, acc[mf][0]);
        acc[mf][1] = MFMA(af, bf1, acc[mf][1]);
      }
    }
  }
#pragma unroll
  for (int fi = 0; fi < 2; ++fi){
    int col = wave*32 + fi*16 + l15;
    float bs = bias[col];
#pragma unroll
    for (int mf = 0; mf < 5; ++mf){
      float v0 = fmaxf(acc[mf][fi][0]+bs, 0.f), v1 = fmaxf(acc[mf][fi][1]+bs, 0.f);
      float v2 = fmaxf(acc[mf][fi][2]+bs, 0.f), v3 = fmaxf(acc[mf][fi][3]+bs, 0.f);
      int tp = (t0 + mf*16 + lq*4) >> 1;
      out[((size_t)b*200 + tp  )*256 + col] = f2bf(fmaxf(v0,v1));
      out[((size_t)b*200 + tp+1)*256 + col] = f2bf(fmaxf(v2,v3));
    }
  }
}

// ---------------- xg GEMM -> permuted xgp layout (512-thread lstm) ----------------
// xgp (bf16): [gi][t][blk][tid512][8], elem = fi*4 + r
// One block stages the A-tile ONCE and loops gi=0..3.
__global__ __launch_bounds__(512) void xg_k(const short* __restrict__ A, const short* __restrict__ W,
                                            const float* __restrict__ bias, short* __restrict__ xg, int mode){
  __shared__ short At[128*264];
  const int M0 = blockIdx.x * 128;
  const int tid = threadIdx.x;
  const int t  = M0 >> 9;
  const int bl = M0 & 511;
  for (int idx = tid; idx < 128*32; idx += 512){
    int i = idx >> 5, c8 = idx & 31;
    int arow = (mode == 0) ? ((bl + i)*200 + t) : (M0 + i);
    *(bf16x8*)(At + i*264 + c8*8) = *(const bf16x8*)(A + (size_t)arow*256 + c8*8);
  }
  __syncthreads();
  const int lane = tid & 63, wave = tid >> 6, l15 = lane & 15, lq = lane >> 4;
  const int blkbase = bl >> 4;
  for (int gi = 0; gi < 4; ++gi){
    const int N0 = gi * 256;
    f32x4 z = {0.f,0.f,0.f,0.f};
    f32x4 acc[8][2];
#pragma unroll
    for (int mf = 0; mf < 8; ++mf){ acc[mf][0] = z; acc[mf][1] = z; }
    for (int ks = 0; ks < 8; ++ks){
      bf16x8 bf0 = *(const bf16x8*)(W + ((size_t)(N0 + wave*32      + l15))*256 + ks*32 + lq*8);
      bf16x8 bf1 = *(const bf16x8*)(W + ((size_t)(N0 + wave*32 + 16 + l15))*256 + ks*32 + lq*8);
#pragma unroll
      for (int mf = 0; mf < 8; ++mf){
        bf16x8 af = *(const bf16x8*)(At + (mf*16 + l15)*264 + ks*32 + lq*8);
        acc[mf][0] = MFMA(af, bf0, acc[mf][0]);
        acc[mf][1] = MFMA(af, bf1, acc[mf][1]);
      }
    }
    const float bs0 = bias[N0 + wave*32 + l15];
    const float bs1 = bias[N0 + wave*32 + 16 + l15];
#pragma unroll
    for (int mf = 0; mf < 8; ++mf){
      bf16x8 vch;
#pragma unroll
      for (int r = 0; r < 4; ++r){
        vch[r]     = f2bf(acc[mf][0][r] + bs0);
        vch[4 + r] = f2bf(acc[mf][1][r] + bs1);
      }
      size_t chunk = (((size_t)gi*200 + t)*32 + blkbase + mf)*512 + wave*64 + lq*16 + l15;
      *(bf16x8*)(xg + chunk*8) = vch;
    }
  }
}

// ---------------- LSTM recurrence (r7 structure): fp8 i/g LDS, fp8 o regs, f bf16 L2-streamed ----------------
// 512 threads, 8 waves x 32 cols. h kept in bf16 + fp8 LDS double-buffers. 1 barrier/step.
__global__ __launch_bounds__(512)
void lstm_k(const short* __restrict__ xgp, const short* __restrict__ whhb,
            const unsigned char* __restrict__ wq8, const float* __restrict__ inv_s,
            short* __restrict__ hseq, float* __restrict__ feat, int mode){
  __shared__ __align__(16) unsigned char wq[2*256*256];   // i, g (XOR-swizzled rows)
  __shared__ __align__(16) unsigned char h8l[2][16*264];  // fp8 h
  __shared__ __align__(16) short hbl[2][16*264];          // bf16 h
  const int blk = blockIdx.x;
  const int b0 = blk * 16;
  const int tid = threadIdx.x, lane = tid & 63, wave = tid >> 6;
  const int l15 = lane & 15, lq = lane >> 4;
  const int j0 = wave * 32;
  const int swz = (l15 & 7) << 4;

  for (int i = tid; i < 16*264; i += 512){ h8l[0][i] = 0; hbl[0][i] = 0; }
  // stage i,g fp8 weights into LDS (swizzled)
  for (int idx = tid; idx < 2*256*16; idx += 512){
    int gg = idx >> 12;
    int rem = idx & 4095;
    int row = rem >> 4, c16 = (rem & 15) << 4;
    uint4 v = *(const uint4*)(wq8 + ((size_t)(gg*256 + row))*256 + c16);
    *(uint4*)(&wq[gg*65536 + row*256 + (c16 ^ ((row & 7) << 4))]) = v;
  }
  // o-gate fp8 fragments pinned in registers: 16 x 8B = 32 VGPRs
  long oreg[2][8];
#pragma unroll
  for (int fi = 0; fi < 2; ++fi)
#pragma unroll
    for (int kk = 0; kk < 8; ++kk)
      oreg[fi][kk] = gload8(wq8 + ((size_t)(2*256 + j0 + fi*16 + l15))*256 + kk*32 + lq*8);
  // dequant scales
  float is_i[2], is_g[2], is_o[2];
#pragma unroll
  for (int fi = 0; fi < 2; ++fi){
    int col = j0 + fi*16 + l15;
    is_i[fi] = inv_s[col];
    is_g[fi] = inv_s[256 + col];
    is_o[fi] = inv_s[512 + col];
  }
  asm volatile("s_waitcnt vmcnt(0)" ::: "memory");

  float c[2][4];
#pragma unroll
  for (int fi=0; fi<2; ++fi)
#pragma unroll
    for (int r=0; r<4; ++r) c[fi][r] = 0.f;

  __syncthreads();

  const size_t GI = (size_t)200*32*512*8;  // per-gi stride in shorts
  bf16x8 xq0, xq1, xq2, xq3;
  {
    const short* p = xgp + (((size_t)0*32 + blk)*512 + tid)*8;
    xq0 = *(const bf16x8*)(p);
    xq1 = *(const bf16x8*)(p + GI);
    xq2 = *(const bf16x8*)(p + 2*GI);
    xq3 = *(const bf16x8*)(p + 3*GI);
  }

  const short* fbase = whhb + (size_t)256*256;  // f-gate rows, bf16
  int cur = 0;

  for (int t = 0; t < 200; ++t){
    const unsigned char* h8c = h8l[cur];
    const short* hbc = hbl[cur];
    f32x4 zz = {0.f,0.f,0.f,0.f};
    f32x4 acc[4][2];
#pragma unroll
    for (int gi=0; gi<4; ++gi){ acc[gi][0] = zz; acc[gi][1] = zz; }
#pragma unroll
    for (int kk = 0; kk < 8; ++kk){
      bf16x8 wf0 = *(const bf16x8*)(fbase + ((size_t)(j0      + l15))*256 + kk*32 + lq*8);
      bf16x8 wf1 = *(const bf16x8*)(fbase + ((size_t)(j0 + 16 + l15))*256 + kk*32 + lq*8);
      bf16x8 avb = *(const bf16x8*)(hbc + l15*264 + kk*32 + lq*8);
      long av8 = *(const long*)(h8c + l15*264 + kk*32 + lq*8);
      int bo = (kk*32 + lq*8) ^ swz;
      long wi0 = *(const long*)(&wq[          (j0      + l15)*256 + bo]);
      long wi1 = *(const long*)(&wq[          (j0 + 16 + l15)*256 + bo]);
      long wg0 = *(const long*)(&wq[65536 +   (j0      + l15)*256 + bo]);
      long wg1 = *(const long*)(&wq[65536 +   (j0 + 16 + l15)*256 + bo]);
      acc[0][0] = MFMA8(av8, wi0, acc[0][0]);
      acc[0][1] = MFMA8(av8, wi1, acc[0][1]);
      acc[1][0] = MFMA (avb, wf0, acc[1][0]);
      acc[1][1] = MFMA (avb, wf1, acc[1][1]);
      acc[2][0] = MFMA8(av8, wg0, acc[2][0]);
      acc[2][1] = MFMA8(av8, wg1, acc[2][1]);
      acc[3][0] = MFMA8(av8, oreg[0][kk], acc[3][0]);
      acc[3][1] = MFMA8(av8, oreg[1][kk], acc[3][1]);
    }
    short hnew[2][4];
    float hfv[2][4];
#pragma unroll
    for (int fi=0; fi<2; ++fi){
#pragma unroll
      for (int r=0; r<4; ++r){
        int e = fi*4 + r;
        float iv = acc[0][fi][r]*is_i[fi] + bf2f(xq0[e]);
        float fv = acc[1][fi][r]          + bf2f(xq1[e]);
        float gv = acc[2][fi][r]*is_g[fi] + bf2f(xq2[e]);
        float ov = acc[3][fi][r]*is_o[fi] + bf2f(xq3[e]);
        float cs = sigm(fv)*c[fi][r] + sigm(iv)*tanh_f(gv);
        c[fi][r] = cs;
        float hv = sigm(ov)*tanh_f(cs);
        hfv[fi][r] = hv;
        hnew[fi][r] = f2bf(hv);
      }
    }
    if (t + 1 < 200){
      const short* p = xgp + (((size_t)(t+1)*32 + blk)*512 + tid)*8;
      xq0 = *(const bf16x8*)(p);
      xq1 = *(const bf16x8*)(p + GI);
      xq2 = *(const bf16x8*)(p + 2*GI);
      xq3 = *(const bf16x8*)(p + 3*GI);
    }
    // write new h (bf16 + fp8) into the other buffers
    short* hbn = hbl[cur ^ 1];
    unsigned char* h8n = h8l[cur ^ 1];
#pragma unroll
    for (int fi=0; fi<2; ++fi){
      int col = j0 + fi*16 + l15;
      unsigned p01 = cvt2_fp8(hfv[fi][0], hfv[fi][1]);
      unsigned p23 = cvt2_fp8(hfv[fi][2], hfv[fi][3]);
      h8n[(lq*4+0)*264 + col] = (unsigned char)(p01 & 0xff);
      h8n[(lq*4+1)*264 + col] = (unsigned char)((p01 >> 8) & 0xff);
      h8n[(lq*4+2)*264 + col] = (unsigned char)(p23 & 0xff);
      h8n[(lq*4+3)*264 + col] = (unsigned char)((p23 >> 8) & 0xff);
#pragma unroll
      for (int r=0; r<4; ++r)
        hbn[(lq*4+r)*264 + col] = hnew[fi][r];
    }
    if (mode == 0){
      short* hs = hseq + ((size_t)t*512 + b0)*256;
#pragma unroll
      for (int fi=0; fi<2; ++fi)
#pragma unroll
        for (int r=0; r<4; ++r)
          hs[(lq*4+r)*256 + j0 + fi*16 + l15] = hnew[fi][r];
    } else if (t == 199){
#pragma unroll
      for (int fi=0; fi<2; ++fi)
#pragma unroll
        for (int r=0; r<4; ++r)
          feat[(size_t)(b0 + lq*4 + r)*256 + j0 + fi*16 + l15] = bf2f(hnew[fi][r]);
    }
    lds_barrier();
    cur ^= 1;
  }
}

// ---------------- gating + feat cast ----------------
__global__ __launch_bounds__(64) void gating_k(const float* __restrict__ feat, const float* __restrict__ gw,
    const float* __restrict__ gb, const float* __restrict__ bg, const float* __restrict__ bb,
    const float* __restrict__ bm, const float* __restrict__ bv,
    float* __restrict__ gating, short* __restrict__ featb){
  const int b = blockIdx.x, lane = threadIdx.x;
  __shared__ float fr[256];
  __shared__ float lg[12];
  for (int i = lane; i < 256; i += 64){
    float v = feat[(size_t)b*256 + i];
    fr[i] = v;
    featb[(size_t)b*256 + i] = f2bf(v);
  }
  __syncthreads();
  if (lane < 12){
    float s = gb[lane];
    for (int k = 0; k < 256; ++k) s += fr[k]*gw[lane*256 + k];
    s = (s - bm[lane])*rsqrtf(bv[lane] + 1e-5f)*bg[lane] + bb[lane];
    lg[lane] = s;
  }
  __syncthreads();
  if (lane == 0){
    float mx = lg[0];
    for (int g = 1; g < 12; ++g) mx = fmaxf(mx, lg[g]);
    float den = 0.f, ex[12];
    for (int g = 0; g < 12; ++g){ ex[g] = __expf(lg[g]-mx); den += ex[g]; }
    for (int g = 0; g < 12; ++g) gating[b*12 + g] = ex[g]/den;
  }
}

// ---------------- MoE experts (atomic accumulate into moe) ----------------
__global__ __launch_bounds__(256) void moe_k(const short* __restrict__ featb, const short* __restrict__ w1t,
    const float* __restrict__ b1, const short* __restrict__ w2t, const float* __restrict__ b2,
    const float* __restrict__ gating, float* __restrict__ moe){
  __shared__ short eh[32*520];
  const int e = blockIdx.x;
  const int b0 = blockIdx.y * 32;
  const int tid = threadIdx.x, lane = tid & 63, wave = tid >> 6;
  const int l15 = lane & 15, lq = lane >> 4;
  f32x4 z = {0.f,0.f,0.f,0.f};
  f32x4 acc[2][8];
#pragma unroll
  for (int nf = 0; nf < 8; ++nf){ acc[0][nf] = z; acc[1][nf] = z; }
  for (int ks = 0; ks < 8; ++ks){
    bf16x8 af0 = *(const bf16x8*)(featb + ((size_t)(b0      + l15))*256 + ks*32 + lq*8);
    bf16x8 af1 = *(const bf16x8*)(featb + ((size_t)(b0 + 16 + l15))*256 + ks*32 + lq*8);
#pragma unroll
    for (int nf = 0; nf < 8; ++nf){
      bf16x8 bf = *(const bf16x8*)(w1t + ((size_t)(e*512 + wave*128 + nf*16 + l15))*256 + ks*32 + lq*8);
      acc[0][nf] = MFMA(af0, bf, acc[0][nf]);
      acc[1][nf] = MFMA(af1, bf, acc[1][nf]);
    }
  }
#pragma unroll
  for (int mf = 0; mf < 2; ++mf){
#pragma unroll
    for (int nf = 0; nf < 8; ++nf){
      int h = wave*128 + nf*16 + l15;
      float bb = b1[e*512 + h];
#pragma unroll
      for (int r = 0; r < 4; ++r){
        float v = acc[mf][nf][r] + bb;
        v = 0.5f*v*(1.f + erff(v*0.70710678118f));
        eh[(mf*16 + lq*4 + r)*520 + h] = f2bf(v);
      }
    }
  }
  __syncthreads();
  f32x4 a2c[2][4];
#pragma unroll
  for (int nf = 0; nf < 4; ++nf){ a2c[0][nf] = z; a2c[1][nf] = z; }
  for (int ks = 0; ks < 16; ++ks){
    bf16x8 af0 = *(const bf16x8*)(eh + (l15     )*520 + ks*32 + lq*8);
    bf16x8 af1 = *(const bf16x8*)(eh + (16 + l15)*520 + ks*32 + lq*8);
#pragma unroll
    for (int nf = 0; nf < 4; ++nf){
      bf16x8 bf = *(const bf16x8*)(w2t + ((size_t)(e*256 + wave*64 + nf*16 + l15))*512 + ks*32 + lq*8);
      a2c[0][nf] = MFMA(af0, bf, a2c[0][nf]);
      a2c[1][nf] = MFMA(af1, bf, a2c[1][nf]);
    }
  }
#pragma unroll
  for (int mf = 0; mf < 2; ++mf){
#pragma unroll
    for (int r = 0; r < 4; ++r){
      int b = b0 + mf*16 + lq*4 + r;
      float ge = gating[b*12 + e];
#pragma unroll
      for (int nf = 0; nf < 4; ++nf){
        int d = wave*64 + nf*16 + l15;
        atomicAdd(&moe[(size_t)b*256 + d], ge*(a2c[mf][nf][r] + b2[e*256 + d]));
      }
    }
  }
}

// ---------------- towers + head + sigmoid ----------------
__global__ __launch_bounds__(256) void tower_k(const float* __restrict__ moe,
    const float* f1sw, const float* f1sb, const float* f2sw, const float* f2sb,
    const float* f3sw, const float* f3sb,
    const float* f1pw, const float* f1pb, const float* f2pw, const float* f2pb,
    const float* f3pw, const float* f3pb,
    const float* hw, const float* hb, float* __restrict__ out){
  __shared__ float mt[16*256];
  __shared__ float h1[2][16][128];
  __shared__ float h2[2][16][64];
  __shared__ float h3[2][16];
  __shared__ float gl[16][2];
  const int b0 = blockIdx.x * 16;
  const int tid = threadIdx.x;
  for (int i = tid; i < 16*256; i += 256) mt[i] = moe[(size_t)b0*256 + i];
  __syncthreads();
  for (int idx = tid; idx < 4096; idx += 256){
    int tower = idx >> 11, b = (idx >> 7) & 15, n = idx & 127;
    const float* w = tower ? f1pw : f1sw;
    float s = (tower ? f1pb : f1sb)[n];
    for (int k = 0; k < 256; ++k) s += mt[b*256 + k]*w[n*256 + k];
    h1[tower][b][n] = fmaxf(s, 0.f);
  }
  __syncthreads();
  for (int idx = tid; idx < 2048; idx += 256){
    int tower = idx >> 10, b = (idx >> 6) & 15, n = idx & 63;
    const float* w = tower ? f2pw : f2sw;
    float s = (tower ? f2pb : f2sb)[n];
    for (int k = 0; k < 128; ++k) s += h1[tower][b][k]*w[n*128 + k];
    h2[tower][b][n] = fmaxf(s, 0.f);
  }
  __syncthreads();
  if (tid < 32){
    int tower = tid >> 4, b = tid & 15;
    const float* w = tower ? f3pw : f3sw;
    float s = (tower ? f3pb : f3sb)[0];
    for (int k = 0; k < 64; ++k) s += h2[tower][b][k]*w[k];
    h3[tower][b] = s;
  } else if (tid < 64){
    int i2 = tid - 32; int b = i2 >> 1, g = i2 & 1;
    float s = hb[g];
    for (int k = 0; k < 256; ++k) s += mt[b*256 + k]*hw[g*256 + k];
    gl[b][g] = s;
  }
  __syncthreads();
  if (tid < 16){
    int b = tid;
    float g0 = 1.f/(1.f + __expf(gl[b][1] - gl[b][0]));
    float val = g0*h3[0][b] + (1.f - g0)*h3[1][b];
    out[b0 + b] = 1.f/(1.f + __expf(-val));
  }
}

// ---------------- host ----------------
extern "C" void kernel_launch(void* const* d_in, const int* in_sizes, int n_in,
                              void* d_out, int out_size, void* d_ws, size_t ws_size,
                              hipStream_t stream){
  (void)in_sizes; (void)n_in; (void)out_size; (void)ws_size;
  const float* x       = (const float*)d_in[0];
  const float* conv1_w = (const float*)d_in[1];
  const float* conv1_b = (const float*)d_in[2];
  const float* bn1_g   = (const float*)d_in[3];
  const float* bn1_b   = (const float*)d_in[4];
  const float* bn1_m   = (const float*)d_in[5];
  const float* bn1_v   = (const float*)d_in[6];
  const float* conv2_w = (const float*)d_in[7];
  const float* conv2_b = (const float*)d_in[8];
  const float* bn2_g   = (const float*)d_in[9];
  const float* bn2_b   = (const float*)d_in[10];
  const float* bn2_m   = (const float*)d_in[11];
  const float* bn2_v   = (const float*)d_in[12];
  const float* wih0    = (const float*)d_in[13];
  const float* whh0    = (const float*)d_in[14];
  const float* bih0    = (const float*)d_in[15];
  const float* bhh0    = (const float*)d_in[16];
  const float* wih1    = (const float*)d_in[17];
  const float* whh1    = (const float*)d_in[18];
  const float* bih1    = (const float*)d_in[19];
  const float* bhh1    = (const float*)d_in[20];
  const float* gate_w  = (const float*)d_in[21];
  const float* gate_b  = (const float*)d_in[22];
  const float* gbn_g   = (const float*)d_in[23];
  const float* gbn_b   = (const float*)d_in[24];
  const float* gbn_m   = (const float*)d_in[25];
  const float* gbn_v   = (const float*)d_in[26];
  const float* exp_w1  = (const float*)d_in[27];
  const float* exp_b1  = (const float*)d_in[28];
  const float* exp_w2  = (const float*)d_in[29];
  const float* exp_b2  = (const float*)d_in[30];
  const float* fc1s_w  = (const float*)d_in[31];
  const float* fc1s_b  = (const float*)d_in[32];
  const float* fc2s_w  = (const float*)d_in[33];
  const float* fc2s_b  = (const float*)d_in[34];
  const float* fc3s_w  = (const float*)d_in[35];
  const float* fc3s_b  = (const float*)d_in[36];
  const float* fc1p_w  = (const float*)d_in[37];
  const float* fc1p_b  = (const float*)d_in[38];
  const float* fc2p_w  = (const float*)d_in[39];
  const float* fc2p_b  = (const float*)d_in[40];
  const float* fc3p_w  = (const float*)d_in[41];
  const float* fc3p_b  = (const float*)d_in[42];
  const float* head_w  = (const float*)d_in[43];
  const float* head_b  = (const float*)d_in[44];
  float* out = (float*)d_out;

  char* base = (char*)d_ws;
  size_t off = 0;
  auto alloc = [&](size_t nbytes)->void*{
    off = (off + 255) & ~(size_t)255;
    void* p = base + off;
    off += nbytes;
    return p;
  };
  short* w1T    = (short*)alloc((size_t)7*128*96*2);
  float* b1c    = (float*)alloc(128*4);
  short* w2T    = (short*)alloc((size_t)7*256*128*2);
  float* b2c    = (float*)alloc(256*4);
  short* wih0b  = (short*)alloc((size_t)1024*256*2);
  short* whh0b  = (short*)alloc((size_t)1024*256*2);
  short* wih1b  = (short*)alloc((size_t)1024*256*2);
  short* whh1b  = (short*)alloc((size_t)1024*256*2);
  float* bias0  = (float*)alloc(1024*4);
  float* bias1  = (float*)alloc(1024*4);
  unsigned char* wq8_0 = (unsigned char*)alloc((size_t)3*256*256);
  unsigned char* wq8_1 = (unsigned char*)alloc((size_t)3*256*256);
  float* invs0  = (float*)alloc(3*256*4);
  float* invs1  = (float*)alloc(3*256*4);
  short* eW1T   = (short*)alloc((size_t)12*512*256*2);
  short* eW2T   = (short*)alloc((size_t)12*256*512*2);
  short* featb  = (short*)alloc((size_t)512*256*2);
  float* gatingb= (float*)alloc((size_t)512*12*4);
  float* moebuf = (float*)alloc((size_t)512*256*4);
  float* featf  = (float*)alloc((size_t)512*256*4);
  short* a1     = (short*)alloc((size_t)512*400*128*2);
  short* a2     = (short*)alloc((size_t)512*200*256*2);
  short* xgbuf  = (short*)alloc((size_t)200*512*1024*2);
  short* h0seq  = a1;  // a1 dead after conv2

  // prep
  prep_convw<<<(7*128*96 + 255)/256, 256, 0, stream>>>(conv1_w, conv1_b, bn1_g, bn1_b, bn1_m, bn1_v, w1T, b1c, 128, 80, 96);
  prep_convw<<<(7*256*128 + 255)/256, 256, 0, stream>>>(conv2_w, conv2_b, bn2_g, bn2_b, bn2_m, bn2_v, w2T, b2c, 256, 128, 128);
  cast_f32_bf16<<<512, 256, 0, stream>>>(wih0, wih0b, 1024*256);
  cast_f32_bf16<<<512, 256, 0, stream>>>(whh0, whh0b, 1024*256);
  cast_f32_bf16<<<512, 256, 0, stream>>>(wih1, wih1b, 1024*256);
  cast_f32_bf16<<<512, 256, 0, stream>>>(whh1, whh1b, 1024*256);
  quant_whh<<<768, 64, 0, stream>>>(whh0, wq8_0, invs0);
  quant_whh<<<768, 64, 0, stream>>>(whh1, wq8_1, invs1);
  add_f32<<<4, 256, 0, stream>>>(bih0, bhh0, bias0, 1024);
  add_f32<<<4, 256, 0, stream>>>(bih1, bhh1, bias1, 1024);
  transp_k<<<(12*512*256 + 255)/256, 256, 0, stream>>>(exp_w1, eW1T, 12, 256, 512);
  transp_k<<<(12*256*512 + 255)/256, 256, 0, stream>>>(exp_w2, eW2T, 12, 512, 256);

  // pipeline
  conv1_k<<<dim3(10, 512), 512, 0, stream>>>(x, w1T, b1c, a1);
  conv2_k<<<dim3(5, 512), 512, 0, stream>>>(a1, w2T, b2c, a2);
  xg_k<<<800, 512, 0, stream>>>(a2, wih0b, bias0, xgbuf, 0);
  lstm_k<<<32, 512, 0, stream>>>(xgbuf, whh0b, wq8_0, invs0, h0seq, nullptr, 0);
  xg_k<<<800, 512, 0, stream>>>(h0seq, wih1b, bias1, xgbuf, 1);
  lstm_k<<<32, 512, 0, stream>>>(xgbuf, whh1b, wq8_1, invs1, nullptr, featf, 1);
  gating_k<<<512, 64, 0, stream>>>(featf, gate_w, gate_b, gbn_g, gbn_b, gbn_m, gbn_v, gatingb, featb);
  hipMemsetAsync(moebuf, 0, (size_t)512*256*4, stream);
  moe_k<<<dim3(12, 16), 256, 0, stream>>>(featb, eW1T, exp_b1, eW2T, exp_b2, gatingb, moebuf);
  tower_k<<<32, 256, 0, stream>>>(moebuf,
      fc1s_w, fc1s_b, fc2s_w, fc2s_b, fc3s_w, fc3s_b,
      fc1p_w, fc1p_b, fc2p_w, fc2p_b, fc3p_w, fc3p_b,
      head_w, head_b, out);
}

// Round 11
// 1996.004 us; speedup vs baseline: 1.4958x; 1.0312x over previous
//
#include <hip/hip_runtime.h>
#include <hip/hip_bf16.h>
#include <math.h>

typedef short bf16x8 __attribute__((ext_vector_type(8)));
typedef float f32x4  __attribute__((ext_vector_type(4)));

__device__ __forceinline__ short f2bf(float f){
  unsigned u = __builtin_bit_cast(unsigned, f);
  u = u + 0x7FFFu + ((u >> 16) & 1u);
  return (short)(u >> 16);
}
__device__ __forceinline__ float bf2f(short h){
  unsigned u = ((unsigned)(unsigned short)h) << 16;
  return __builtin_bit_cast(float, u);
}
// single-instruction v_rcp_f32 (~1ulp) instead of the ~7-inst exact-div sequence
__device__ __forceinline__ float sigm(float x){
  return __builtin_amdgcn_rcpf(1.f + __expf(-x));
}
__device__ __forceinline__ float tanh_f(float x){
  float e = __expf(-2.f*x);
  return (1.f - e) * __builtin_amdgcn_rcpf(1.f + e);
}

// f32 -> OCP e4m3fn with RNE (for weight quantization in prep)
__device__ __forceinline__ unsigned char f2e4m3(float f){
  unsigned u = __builtin_bit_cast(unsigned, f);
  unsigned s = (u >> 24) & 0x80u;
  float af = fabsf(f);
  if (!(af < 448.f)) return (unsigned char)(s | 0x7E);
  if (af < 0.015625f){
    int q = (int)(af * 512.f + 0.5f);
    return (unsigned char)(s | (unsigned)q);
  }
  int e = (int)((u >> 23) & 0xff) - 127;
  unsigned m = u & 0x7fffffu;
  unsigned mant = m >> 20;
  unsigned rem = m & 0xfffffu;
  if (rem > 0x80000u || (rem == 0x80000u && (mant & 1u))) mant++;
  if (mant == 8u){ mant = 0u; e++; if (e > 8) return (unsigned char)(s | 0x7E); }
  return (unsigned char)(s | ((unsigned)(e + 7) << 3) | mant);
}

// HW packed f32->fp8 (e4m3fn on gfx950), byte0=a, byte1=b
__device__ __forceinline__ unsigned cvt2_fp8(float a, float b){
  unsigned r;
  asm volatile("v_cvt_pk_fp8_f32 %0, %1, %2" : "=v"(r) : "v"(a), "v"(b));
  return r;
}

// LDS-only barrier: waits LDS ops, leaves global loads/stores in flight
__device__ __forceinline__ void lds_barrier(){
  asm volatile("s_waitcnt lgkmcnt(0)" ::: "memory");
  __builtin_amdgcn_s_barrier();
  __builtin_amdgcn_sched_barrier(0);
}

// Opaque 8B global load: cannot be rematerialized/CSE'd -> stays register-resident.
__device__ __forceinline__ long gload8(const void* p){
  long r;
  asm volatile("global_load_dwordx2 %0, %1, off" : "=v"(r) : "v"(p));
  return r;
}

#define MFMA(a,b,c)  __builtin_amdgcn_mfma_f32_16x16x32_bf16((a),(b),(c),0,0,0)
#define MFMA8(a,b,c) __builtin_amdgcn_mfma_f32_16x16x32_fp8_fp8((a),(b),(c),0,0,0)

// ---------------- prep kernels ----------------

__global__ void prep_convw(const float* __restrict__ w, const float* __restrict__ cb,
                           const float* __restrict__ g, const float* __restrict__ bb,
                           const float* __restrict__ m, const float* __restrict__ v,
                           short* __restrict__ wT, float* __restrict__ bias,
                           int O, int I, int Cpad){
  int idx = blockIdx.x*blockDim.x + threadIdx.x;
  int total = 7*O*Cpad;
  if (idx < total){
    int kt = idx / (O*Cpad);
    int rem = idx - kt*O*Cpad;
    int n = rem / Cpad;
    int c = rem - n*Cpad;
    float s = g[n] * rsqrtf(v[n] + 1e-5f);
    float val = (c < I) ? w[((size_t)n*I + c)*7 + kt] * s : 0.f;
    wT[idx] = f2bf(val);
  }
  if (idx < O){
    float s = g[idx] * rsqrtf(v[idx] + 1e-5f);
    bias[idx] = (cb[idx] - m[idx]) * s + bb[idx];
  }
}

__global__ void cast_f32_bf16(const float* __restrict__ src, short* __restrict__ dst, int n){
  int i = blockIdx.x*blockDim.x + threadIdx.x;
  int stride = gridDim.x*blockDim.x;
  for (; i < n; i += stride) dst[i] = f2bf(src[i]);
}

__global__ void add_f32(const float* __restrict__ a, const float* __restrict__ b, float* __restrict__ c, int n){
  int i = blockIdx.x*blockDim.x + threadIdx.x;
  if (i < n) c[i] = a[i] + b[i];
}

// small f32 transpose: in[R][C] -> out[C][R] (tiny matrices, prep only)
__global__ void transpf(const float* __restrict__ in, float* __restrict__ out, int R, int C){
  int idx = blockIdx.x*blockDim.x + threadIdx.x;
  if (idx >= R*C) return;
  int r = idx / C, c = idx - r*C;
  out[(size_t)c*R + r] = in[idx];
}

// in [e][K][N] f32 -> out [e][N][K] bf16 -- 64x64 LDS tile transpose, both phases coalesced
__global__ __launch_bounds__(256) void transp_k(const float* __restrict__ in, short* __restrict__ out,
                                                int E, int K, int N){
  __shared__ float tile[64][65];
  const int nt = N >> 6, kt = K >> 6;
  const int e = blockIdx.x / (nt*kt);
  const int rem = blockIdx.x - e*nt*kt;
  const int k0 = (rem / nt) << 6;
  const int n0 = (rem - (rem/nt)*nt) << 6;
  const int tc = threadIdx.x & 63, tr = threadIdx.x >> 6;
#pragma unroll 4
  for (int p = 0; p < 16; ++p){
    int k = p*4 + tr;
    tile[k][tc] = in[((size_t)e*K + k0 + k)*N + n0 + tc];
  }
  __syncthreads();
#pragma unroll 4
  for (int p = 0; p < 16; ++p){
    int n = p*4 + tr;
    out[((size_t)e*N + n0 + n)*K + k0 + tc] = f2bf(tile[tc][n]);
  }
}

// quantize whh gate rows {i:0-255, g:512-767, o:768-1023} to fp8 e4m3, per-row scale.
__global__ __launch_bounds__(64) void quant_whh(const float* __restrict__ whh,
                                                unsigned char* __restrict__ wq8,
                                                float* __restrict__ inv_s){
  const int rb = blockIdx.x;          // 0..767
  const int gsel = rb >> 8;           // 0=i, 1=g, 2=o
  const int r = rb & 255;
  const int srow = (gsel == 0 ? 0 : (gsel == 1 ? 512 : 768)) + r;
  const int lane = threadIdx.x;
  const float* wr = whh + (size_t)srow*256;
  float v4[4];
  float mx = 0.f;
#pragma unroll
  for (int j = 0; j < 4; ++j){ v4[j] = wr[lane*4 + j]; mx = fmaxf(mx, fabsf(v4[j])); }
#pragma unroll
  for (int off = 32; off >= 1; off >>= 1) mx = fmaxf(mx, __shfl_xor(mx, off));
  float s = (mx > 0.f) ? (448.f / mx) : 1.f;
  if (lane == 0) inv_s[gsel*256 + r] = (mx > 0.f) ? (mx / 448.f) : 0.f;
  unsigned w = 0;
#pragma unroll
  for (int j = 0; j < 4; ++j) w |= ((unsigned)f2e4m3(v4[j]*s)) << (8*j);
  *(unsigned*)(wq8 + ((size_t)(gsel*256 + r))*256 + lane*4) = w;
}

// ---------------- conv1: x(512,80,800)f32 -> a1[b][400][128] bf16 ----------------
#define C1_ROWS 86
#define C1_PITCH 104
__global__ __launch_bounds__(512) void conv1_k(const float* __restrict__ x, const short* __restrict__ wT,
                                               const float* __restrict__ bias, short* __restrict__ out){
  __shared__ short At[C1_ROWS*C1_PITCH];
  const int b = blockIdx.y;
  const int t0 = blockIdx.x * 80;
  const int tid = threadIdx.x;
  for (int i = tid; i < C1_ROWS*C1_PITCH; i += 512) At[i] = 0;
  __syncthreads();
  for (int idx = tid; idx < 80*C1_ROWS; idx += 512){
    int c = idx / C1_ROWS, i = idx - c*C1_ROWS;
    int t = t0 - 3 + i;
    float v = (t >= 0 && t < 800) ? x[((size_t)b*80 + c)*800 + t] : 0.f;
    At[i*C1_PITCH + c] = f2bf(v);
  }
  __syncthreads();
  const int lane = tid & 63, wave = tid >> 6;
  const int l15 = lane & 15, lq = lane >> 4;
  const int col = wave*16 + l15;
  f32x4 z = {0.f,0.f,0.f,0.f};
  f32x4 acc[5] = {z,z,z,z,z};
  for (int kt = 0; kt < 7; ++kt){
    for (int ks = 0; ks < 3; ++ks){
      bf16x8 bf = *(const bf16x8*)(wT + ((size_t)(kt*128 + col))*96 + ks*32 + lq*8);
#pragma unroll
      for (int mf = 0; mf < 5; ++mf){
        bf16x8 af = *(const bf16x8*)(At + (mf*16 + l15 + kt)*C1_PITCH + ks*32 + lq*8);
        acc[mf] = MFMA(af, bf, acc[mf]);
      }
    }
  }
  const float bs = bias[col];
#pragma unroll
  for (int mf = 0; mf < 5; ++mf){
    float v0 = fmaxf(acc[mf][0]+bs, 0.f), v1 = fmaxf(acc[mf][1]+bs, 0.f);
    float v2 = fmaxf(acc[mf][2]+bs, 0.f), v3 = fmaxf(acc[mf][3]+bs, 0.f);
    int tp = (t0 + mf*16 + lq*4) >> 1;
    out[((size_t)b*400 + tp  )*128 + col] = f2bf(fmaxf(v0,v1));
    out[((size_t)b*400 + tp+1)*128 + col] = f2bf(fmaxf(v2,v3));
  }
}

// ---------------- conv2: a1[b][400][128] -> a2[b][200][256] bf16 ----------------
#define C2_ROWS 86
#define C2_PITCH 136
__global__ __launch_bounds__(512) void conv2_k(const short* __restrict__ a1, const short* __restrict__ wT,
                                               const float* __restrict__ bias, short* __restrict__ out){
  __shared__ short At[C2_ROWS*C2_PITCH];
  const int b = blockIdx.y;
  const int t0 = blockIdx.x * 80;
  const int tid = threadIdx.x;
  bf16x8 zb = {0,0,0,0,0,0,0,0};
  for (int idx = tid; idx < C2_ROWS*16; idx += 512){
    int i = idx >> 4, c8 = idx & 15;
    int t = t0 - 3 + i;
    bf16x8 v = zb;
    if (t >= 0 && t < 400) v = *(const bf16x8*)(a1 + ((size_t)b*400 + t)*128 + c8*8);
    *(bf16x8*)(At + i*C2_PITCH + c8*8) = v;
  }
  __syncthreads();
  const int lane = tid & 63, wave = tid >> 6;
  const int l15 = lane & 15, lq = lane >> 4;
  f32x4 z = {0.f,0.f,0.f,0.f};
  f32x4 acc[5][2];
#pragma unroll
  for (int mf = 0; mf < 5; ++mf){ acc[mf][0] = z; acc[mf][1] = z; }
  for (int kt = 0; kt < 7; ++kt){
    for (int ks = 0; ks < 4; ++ks){
      bf16x8 bf0 = *(const bf16x8*)(wT + ((size_t)(kt*256 + wave*32      + l15))*128 + ks*32 + lq*8);
      bf16x8 bf1 = *(const bf16x8*)(wT + ((size_t)(kt*256 + wave*32 + 16 + l15))*128 + ks*32 + lq*8);
#pragma unroll
      for (int mf = 0; mf < 5; ++mf){
        bf16x8 af = *(const bf16x8*)(At + (mf*16 + l15 + kt)*C2_PITCH + ks*32 + lq*8);
        acc[mf][0] = MFMA(af, bf0, acc[mf][0]);
        acc[mf][1] = MFMA(af, bf1, acc[mf][1]);
      }
    }
  }
#pragma unroll
  for (int fi = 0; fi < 2; ++fi){
    int col = wave*32 + fi*16 + l15;
    float bs = bias[col];
#pragma unroll
    for (int mf = 0; mf < 5; ++mf){
      float v0 = fmaxf(acc[mf][fi][0]+bs, 0.f), v1 = fmaxf(acc[mf][fi][1]+bs, 0.f);
      float v2 = fmaxf(acc[mf][fi][2]+bs, 0.f), v3 = fmaxf(acc[mf][fi][3]+bs, 0.f);
      int tp = (t0 + mf*16 + lq*4) >> 1;
      out[((size_t)b*200 + tp  )*256 + col] = f2bf(fmaxf(v0,v1));
      out[((size_t)b*200 + tp+1)*256 + col] = f2bf(fmaxf(v2,v3));
    }
  }
}

// ---------------- xg GEMM -> permuted xgp layout (512-thread lstm) ----------------
__global__ __launch_bounds__(512) void xg_k(const short* __restrict__ A, const short* __restrict__ W,
                                            const float* __restrict__ bias, short* __restrict__ xg, int mode){
  __shared__ short At[128*264];
  const int M0 = blockIdx.x * 128;
  const int tid = threadIdx.x;
  const int t  = M0 >> 9;
  const int bl = M0 & 511;
  for (int idx = tid; idx < 128*32; idx += 512){
    int i = idx >> 5, c8 = idx & 31;
    int arow = (mode == 0) ? ((bl + i)*200 + t) : (M0 + i);
    *(bf16x8*)(At + i*264 + c8*8) = *(const bf16x8*)(A + (size_t)arow*256 + c8*8);
  }
  __syncthreads();
  const int lane = tid & 63, wave = tid >> 6, l15 = lane & 15, lq = lane >> 4;
  const int blkbase = bl >> 4;
  for (int gi = 0; gi < 4; ++gi){
    const int N0 = gi * 256;
    f32x4 z = {0.f,0.f,0.f,0.f};
    f32x4 acc[8][2];
#pragma unroll
    for (int mf = 0; mf < 8; ++mf){ acc[mf][0] = z; acc[mf][1] = z; }
    for (int ks = 0; ks < 8; ++ks){
      bf16x8 bf0 = *(const bf16x8*)(W + ((size_t)(N0 + wave*32      + l15))*256 + ks*32 + lq*8);
      bf16x8 bf1 = *(const bf16x8*)(W + ((size_t)(N0 + wave*32 + 16 + l15))*256 + ks*32 + lq*8);
#pragma unroll
      for (int mf = 0; mf < 8; ++mf){
        bf16x8 af = *(const bf16x8*)(At + (mf*16 + l15)*264 + ks*32 + lq*8);
        acc[mf][0] = MFMA(af, bf0, acc[mf][0]);
        acc[mf][1] = MFMA(af, bf1, acc[mf][1]);
      }
    }
    const float bs0 = bias[N0 + wave*32 + l15];
    const float bs1 = bias[N0 + wave*32 + 16 + l15];
#pragma unroll
    for (int mf = 0; mf < 8; ++mf){
      bf16x8 vch;
#pragma unroll
      for (int r = 0; r < 4; ++r){
        vch[r]     = f2bf(acc[mf][0][r] + bs0);
        vch[4 + r] = f2bf(acc[mf][1][r] + bs1);
      }
      size_t chunk = (((size_t)gi*200 + t)*32 + blkbase + mf)*512 + wave*64 + lq*16 + l15;
      *(bf16x8*)(xg + chunk*8) = vch;
    }
  }
}

// ---------------- LSTM recurrence (r7 structure): fp8 i/g LDS, fp8 o regs, f bf16 L2-streamed ----------------
__global__ __launch_bounds__(512)
void lstm_k(const short* __restrict__ xgp, const short* __restrict__ whhb,
            const unsigned char* __restrict__ wq8, const float* __restrict__ inv_s,
            short* __restrict__ hseq, float* __restrict__ feat, int mode){
  __shared__ __align__(16) unsigned char wq[2*256*256];   // i, g (XOR-swizzled rows)
  __shared__ __align__(16) unsigned char h8l[2][16*264];  // fp8 h
  __shared__ __align__(16) short hbl[2][16*264];          // bf16 h
  const int blk = blockIdx.x;
  const int b0 = blk * 16;
  const int tid = threadIdx.x, lane = tid & 63, wave = tid >> 6;
  const int l15 = lane & 15, lq = lane >> 4;
  const int j0 = wave * 32;
  const int swz = (l15 & 7) << 4;

  for (int i = tid; i < 16*264; i += 512){ h8l[0][i] = 0; hbl[0][i] = 0; }
  for (int idx = tid; idx < 2*256*16; idx += 512){
    int gg = idx >> 12;
    int rem = idx & 4095;
    int row = rem >> 4, c16 = (rem & 15) << 4;
    uint4 v = *(const uint4*)(wq8 + ((size_t)(gg*256 + row))*256 + c16);
    *(uint4*)(&wq[gg*65536 + row*256 + (c16 ^ ((row & 7) << 4))]) = v;
  }
  long oreg[2][8];
#pragma unroll
  for (int fi = 0; fi < 2; ++fi)
#pragma unroll
    for (int kk = 0; kk < 8; ++kk)
      oreg[fi][kk] = gload8(wq8 + ((size_t)(2*256 + j0 + fi*16 + l15))*256 + kk*32 + lq*8);
  float is_i[2], is_g[2], is_o[2];
#pragma unroll
  for (int fi = 0; fi < 2; ++fi){
    int col = j0 + fi*16 + l15;
    is_i[fi] = inv_s[col];
    is_g[fi] = inv_s[256 + col];
    is_o[fi] = inv_s[512 + col];
  }
  asm volatile("s_waitcnt vmcnt(0)" ::: "memory");

  float c[2][4];
#pragma unroll
  for (int fi=0; fi<2; ++fi)
#pragma unroll
    for (int r=0; r<4; ++r) c[fi][r] = 0.f;

  __syncthreads();

  const size_t GI = (size_t)200*32*512*8;
  bf16x8 xq0, xq1, xq2, xq3;
  {
    const short* p = xgp + (((size_t)0*32 + blk)*512 + tid)*8;
    xq0 = *(const bf16x8*)(p);
    xq1 = *(const bf16x8*)(p + GI);
    xq2 = *(const bf16x8*)(p + 2*GI);
    xq3 = *(const bf16x8*)(p + 3*GI);
  }

  const short* fbase = whhb + (size_t)256*256;
  int cur = 0;

  for (int t = 0; t < 200; ++t){
    const unsigned char* h8c = h8l[cur];
    const short* hbc = hbl[cur];
    f32x4 zz = {0.f,0.f,0.f,0.f};
    f32x4 acc[4][2];
#pragma unroll
    for (int gi=0; gi<4; ++gi){ acc[gi][0] = zz; acc[gi][1] = zz; }
#pragma unroll
    for (int kk = 0; kk < 8; ++kk){
      bf16x8 wf0 = *(const bf16x8*)(fbase + ((size_t)(j0      + l15))*256 + kk*32 + lq*8);
      bf16x8 wf1 = *(const bf16x8*)(fbase + ((size_t)(j0 + 16 + l15))*256 + kk*32 + lq*8);
      bf16x8 avb = *(const bf16x8*)(hbc + l15*264 + kk*32 + lq*8);
      long av8 = *(const long*)(h8c + l15*264 + kk*32 + lq*8);
      int bo = (kk*32 + lq*8) ^ swz;
      long wi0 = *(const long*)(&wq[          (j0      + l15)*256 + bo]);
      long wi1 = *(const long*)(&wq[          (j0 + 16 + l15)*256 + bo]);
      long wg0 = *(const long*)(&wq[65536 +   (j0      + l15)*256 + bo]);
      long wg1 = *(const long*)(&wq[65536 +   (j0 + 16 + l15)*256 + bo]);
      acc[0][0] = MFMA8(av8, wi0, acc[0][0]);
      acc[0][1] = MFMA8(av8, wi1, acc[0][1]);
      acc[1][0] = MFMA (avb, wf0, acc[1][0]);
      acc[1][1] = MFMA (avb, wf1, acc[1][1]);
      acc[2][0] = MFMA8(av8, wg0, acc[2][0]);
      acc[2][1] = MFMA8(av8, wg1, acc[2][1]);
      acc[3][0] = MFMA8(av8, oreg[0][kk], acc[3][0]);
      acc[3][1] = MFMA8(av8, oreg[1][kk], acc[3][1]);
    }
    short hnew[2][4];
    float hfv[2][4];
#pragma unroll
    for (int fi=0; fi<2; ++fi){
#pragma unroll
      for (int r=0; r<4; ++r){
        int e = fi*4 + r;
        float iv = acc[0][fi][r]*is_i[fi] + bf2f(xq0[e]);
        float fv = acc[1][fi][r]          + bf2f(xq1[e]);
        float gv = acc[2][fi][r]*is_g[fi] + bf2f(xq2[e]);
        float ov = acc[3][fi][r]*is_o[fi] + bf2f(xq3[e]);
        float cs = sigm(fv)*c[fi][r] + sigm(iv)*tanh_f(gv);
        c[fi][r] = cs;
        float hv = sigm(ov)*tanh_f(cs);
        hfv[fi][r] = hv;
        hnew[fi][r] = f2bf(hv);
      }
    }
    if (t + 1 < 200){
      const short* p = xgp + (((size_t)(t+1)*32 + blk)*512 + tid)*8;
      xq0 = *(const bf16x8*)(p);
      xq1 = *(const bf16x8*)(p + GI);
      xq2 = *(const bf16x8*)(p + 2*GI);
      xq3 = *(const bf16x8*)(p + 3*GI);
    }
    short* hbn = hbl[cur ^ 1];
    unsigned char* h8n = h8l[cur ^ 1];
#pragma unroll
    for (int fi=0; fi<2; ++fi){
      int col = j0 + fi*16 + l15;
      unsigned p01 = cvt2_fp8(hfv[fi][0], hfv[fi][1]);
      unsigned p23 = cvt2_fp8(hfv[fi][2], hfv[fi][3]);
      h8n[(lq*4+0)*264 + col] = (unsigned char)(p01 & 0xff);
      h8n[(lq*4+1)*264 + col] = (unsigned char)((p01 >> 8) & 0xff);
      h8n[(lq*4+2)*264 + col] = (unsigned char)(p23 & 0xff);
      h8n[(lq*4+3)*264 + col] = (unsigned char)((p23 >> 8) & 0xff);
#pragma unroll
      for (int r=0; r<4; ++r)
        hbn[(lq*4+r)*264 + col] = hnew[fi][r];
    }
    if (mode == 0){
      short* hs = hseq + ((size_t)t*512 + b0)*256;
#pragma unroll
      for (int fi=0; fi<2; ++fi)
#pragma unroll
        for (int r=0; r<4; ++r)
          hs[(lq*4+r)*256 + j0 + fi*16 + l15] = hnew[fi][r];
    } else if (t == 199){
#pragma unroll
      for (int fi=0; fi<2; ++fi)
#pragma unroll
        for (int r=0; r<4; ++r)
          feat[(size_t)(b0 + lq*4 + r)*256 + j0 + fi*16 + l15] = bf2f(hnew[fi][r]);
    }
    lds_barrier();
    cur ^= 1;
  }
}

// ---------------- gating + feat cast (all-lane cooperative dots) ----------------
__global__ __launch_bounds__(64) void gating_k(const float* __restrict__ feat, const float* __restrict__ gw,
    const float* __restrict__ gb, const float* __restrict__ bg, const float* __restrict__ bb,
    const float* __restrict__ bm, const float* __restrict__ bv,
    float* __restrict__ gating, short* __restrict__ featb){
  const int b = blockIdx.x, lane = threadIdx.x;
  __shared__ float fr[256];
  float lg[12];
  for (int i = lane; i < 256; i += 64){
    float v = feat[(size_t)b*256 + i];
    fr[i] = v;
    featb[(size_t)b*256 + i] = f2bf(v);
  }
  __syncthreads();
  for (int g = 0; g < 12; ++g){
    float s = 0.f;
#pragma unroll
    for (int kc = 0; kc < 4; ++kc){
      int k = kc*64 + lane;
      s += fr[k]*gw[g*256 + k];
    }
#pragma unroll
    for (int off = 32; off >= 1; off >>= 1) s += __shfl_xor(s, off);
    lg[g] = s;  // all lanes hold the full sum
  }
  if (lane == 0){
    float mx = -1e30f;
    for (int g = 0; g < 12; ++g){
      float s = lg[g] + gb[g];
      s = (s - bm[g])*rsqrtf(bv[g] + 1e-5f)*bg[g] + bb[g];
      lg[g] = s;
      mx = fmaxf(mx, s);
    }
    float den = 0.f, ex[12];
    for (int g = 0; g < 12; ++g){ ex[g] = __expf(lg[g]-mx); den += ex[g]; }
    float rd = __builtin_amdgcn_rcpf(den);
    for (int g = 0; g < 12; ++g) gating[b*12 + g] = ex[g]*rd;
  }
}

// ---------------- MoE experts (atomic accumulate into moe) ----------------
__global__ __launch_bounds__(256) void moe_k(const short* __restrict__ featb, const short* __restrict__ w1t,
    const float* __restrict__ b1, const short* __restrict__ w2t, const float* __restrict__ b2,
    const float* __restrict__ gating, float* __restrict__ moe){
  __shared__ short eh[32*520];
  const int e = blockIdx.x;
  const int b0 = blockIdx.y * 32;
  const int tid = threadIdx.x, lane = tid & 63, wave = tid >> 6;
  const int l15 = lane & 15, lq = lane >> 4;
  f32x4 z = {0.f,0.f,0.f,0.f};
  f32x4 acc[2][8];
#pragma unroll
  for (int nf = 0; nf < 8; ++nf){ acc[0][nf] = z; acc[1][nf] = z; }
  for (int ks = 0; ks < 8; ++ks){
    bf16x8 af0 = *(const bf16x8*)(featb + ((size_t)(b0      + l15))*256 + ks*32 + lq*8);
    bf16x8 af1 = *(const bf16x8*)(featb + ((size_t)(b0 + 16 + l15))*256 + ks*32 + lq*8);
#pragma unroll
    for (int nf = 0; nf < 8; ++nf){
      bf16x8 bf = *(const bf16x8*)(w1t + ((size_t)(e*512 + wave*128 + nf*16 + l15))*256 + ks*32 + lq*8);
      acc[0][nf] = MFMA(af0, bf, acc[0][nf]);
      acc[1][nf] = MFMA(af1, bf, acc[1][nf]);
    }
  }
#pragma unroll
  for (int mf = 0; mf < 2; ++mf){
#pragma unroll
    for (int nf = 0; nf < 8; ++nf){
      int h = wave*128 + nf*16 + l15;
      float bb = b1[e*512 + h];
#pragma unroll
      for (int r = 0; r < 4; ++r){
        float v = acc[mf][nf][r] + bb;
        v = 0.5f*v*(1.f + erff(v*0.70710678118f));
        eh[(mf*16 + lq*4 + r)*520 + h] = f2bf(v);
      }
    }
  }
  __syncthreads();
  f32x4 a2c[2][4];
#pragma unroll
  for (int nf = 0; nf < 4; ++nf){ a2c[0][nf] = z; a2c[1][nf] = z; }
  for (int ks = 0; ks < 16; ++ks){
    bf16x8 af0 = *(const bf16x8*)(eh + (l15     )*520 + ks*32 + lq*8);
    bf16x8 af1 = *(const bf16x8*)(eh + (16 + l15)*520 + ks*32 + lq*8);
#pragma unroll
    for (int nf = 0; nf < 4; ++nf){
      bf16x8 bf = *(const bf16x8*)(w2t + ((size_t)(e*256 + wave*64 + nf*16 + l15))*512 + ks*32 + lq*8);
      a2c[0][nf] = MFMA(af0, bf, a2c[0][nf]);
      a2c[1][nf] = MFMA(af1, bf, a2c[1][nf]);
    }
  }
#pragma unroll
  for (int mf = 0; mf < 2; ++mf){
#pragma unroll
    for (int r = 0; r < 4; ++r){
      int b = b0 + mf*16 + lq*4 + r;
      float ge = gating[b*12 + e];
#pragma unroll
      for (int nf = 0; nf < 4; ++nf){
        int d = wave*64 + nf*16 + l15;
        atomicAdd(&moe[(size_t)b*256 + d], ge*(a2c[mf][nf][r] + b2[e*256 + d]));
      }
    }
  }
}

// ---------------- towers + head + sigmoid (transposed fc weights, coalesced) ----------------
__global__ __launch_bounds__(256) void tower_k(const float* __restrict__ moe,
    const float* f1sT, const float* f1sb, const float* f2sT, const float* f2sb,
    const float* f3sw, const float* f3sb,
    const float* f1pT, const float* f1pb, const float* f2pT, const float* f2pb,
    const float* f3pw, const float* f3pb,
    const float* hw, const float* hb, float* __restrict__ out){
  __shared__ float mt[16*256];
  __shared__ float h1[2][16][128];
  __shared__ float h2[2][16][64];
  __shared__ float h3[2][16];
  __shared__ float gl[16][2];
  const int b0 = blockIdx.x * 16;
  const int tid = threadIdx.x;
  for (int i = tid; i < 16*256; i += 256) mt[i] = moe[(size_t)b0*256 + i];
  __syncthreads();
  for (int idx = tid; idx < 4096; idx += 256){
    int tower = idx >> 11, b = (idx >> 7) & 15, n = idx & 127;
    const float* wT = tower ? f1pT : f1sT;   // [256][128]
    float s = (tower ? f1pb : f1sb)[n];
    for (int k = 0; k < 256; ++k) s += mt[b*256 + k]*wT[k*128 + n];
    h1[tower][b][n] = fmaxf(s, 0.f);
  }
  __syncthreads();
  for (int idx = tid; idx < 2048; idx += 256){
    int tower = idx >> 10, b = (idx >> 6) & 15, n = idx & 63;
    const float* wT = tower ? f2pT : f2sT;   // [128][64]
    float s = (tower ? f2pb : f2sb)[n];
    for (int k = 0; k < 128; ++k) s += h1[tower][b][k]*wT[k*64 + n];
    h2[tower][b][n] = fmaxf(s, 0.f);
  }
  __syncthreads();
  if (tid < 32){
    int tower = tid >> 4, b = tid & 15;
    const float* w = tower ? f3pw : f3sw;
    float s = (tower ? f3pb : f3sb)[0];
    for (int k = 0; k < 64; ++k) s += h2[tower][b][k]*w[k];
    h3[tower][b] = s;
  } else if (tid < 64){
    int i2 = tid - 32; int b = i2 >> 1, g = i2 & 1;
    float s = hb[g];
    for (int k = 0; k < 256; ++k) s += mt[b*256 + k]*hw[g*256 + k];
    gl[b][g] = s;
  }
  __syncthreads();
  if (tid < 16){
    int b = tid;
    float g0 = 1.f/(1.f + __expf(gl[b][1] - gl[b][0]));
    float val = g0*h3[0][b] + (1.f - g0)*h3[1][b];
    out[b0 + b] = 1.f/(1.f + __expf(-val));
  }
}

// ---------------- host ----------------
extern "C" void kernel_launch(void* const* d_in, const int* in_sizes, int n_in,
                              void* d_out, int out_size, void* d_ws, size_t ws_size,
                              hipStream_t stream){
  (void)in_sizes; (void)n_in; (void)out_size; (void)ws_size;
  const float* x       = (const float*)d_in[0];
  const float* conv1_w = (const float*)d_in[1];
  const float* conv1_b = (const float*)d_in[2];
  const float* bn1_g   = (const float*)d_in[3];
  const float* bn1_b   = (const float*)d_in[4];
  const float* bn1_m   = (const float*)d_in[5];
  const float* bn1_v   = (const float*)d_in[6];
  const float* conv2_w = (const float*)d_in[7];
  const float* conv2_b = (const float*)d_in[8];
  const float* bn2_g   = (const float*)d_in[9];
  const float* bn2_b   = (const float*)d_in[10];
  const float* bn2_m   = (const float*)d_in[11];
  const float* bn2_v   = (const float*)d_in[12];
  const float* wih0    = (const float*)d_in[13];
  const float* whh0    = (const float*)d_in[14];
  const float* bih0    = (const float*)d_in[15];
  const float* bhh0    = (const float*)d_in[16];
  const float* wih1    = (const float*)d_in[17];
  const float* whh1    = (const float*)d_in[18];
  const float* bih1    = (const float*)d_in[19];
  const float* bhh1    = (const float*)d_in[20];
  const float* gate_w  = (const float*)d_in[21];
  const float* gate_b  = (const float*)d_in[22];
  const float* gbn_g   = (const float*)d_in[23];
  const float* gbn_b   = (const float*)d_in[24];
  const float* gbn_m   = (const float*)d_in[25];
  const float* gbn_v   = (const float*)d_in[26];
  const float* exp_w1  = (const float*)d_in[27];
  const float* exp_b1  = (const float*)d_in[28];
  const float* exp_w2  = (const float*)d_in[29];
  const float* exp_b2  = (const float*)d_in[30];
  const float* fc1s_w  = (const float*)d_in[31];
  const float* fc1s_b  = (const float*)d_in[32];
  const float* fc2s_w  = (const float*)d_in[33];
  const float* fc2s_b  = (const float*)d_in[34];
  const float* fc3s_w  = (const float*)d_in[35];
  const float* fc3s_b  = (const float*)d_in[36];
  const float* fc1p_w  = (const float*)d_in[37];
  const float* fc1p_b  = (const float*)d_in[38];
  const float* fc2p_w  = (const float*)d_in[39];
  const float* fc2p_b  = (const float*)d_in[40];
  const float* fc3p_w  = (const float*)d_in[41];
  const float* fc3p_b  = (const float*)d_in[42];
  const float* head_w  = (const float*)d_in[43];
  const float* head_b  = (const float*)d_in[44];
  float* out = (float*)d_out;

  char* base = (char*)d_ws;
  size_t off = 0;
  auto alloc = [&](size_t nbytes)->void*{
    off = (off + 255) & ~(size_t)255;
    void* p = base + off;
    off += nbytes;
    return p;
  };
  short* w1T    = (short*)alloc((size_t)7*128*96*2);
  float* b1c    = (float*)alloc(128*4);
  short* w2T    = (short*)alloc((size_t)7*256*128*2);
  float* b2c    = (float*)alloc(256*4);
  short* wih0b  = (short*)alloc((size_t)1024*256*2);
  short* whh0b  = (short*)alloc((size_t)1024*256*2);
  short* wih1b  = (short*)alloc((size_t)1024*256*2);
  short* whh1b  = (short*)alloc((size_t)1024*256*2);
  float* bias0  = (float*)alloc(1024*4);
  float* bias1  = (float*)alloc(1024*4);
  unsigned char* wq8_0 = (unsigned char*)alloc((size_t)3*256*256);
  unsigned char* wq8_1 = (unsigned char*)alloc((size_t)3*256*256);
  float* invs0  = (float*)alloc(3*256*4);
  float* invs1  = (float*)alloc(3*256*4);
  short* eW1T   = (short*)alloc((size_t)12*512*256*2);
  short* eW2T   = (short*)alloc((size_t)12*256*512*2);
  float* f1sT   = (float*)alloc((size_t)256*128*4);
  float* f1pT   = (float*)alloc((size_t)256*128*4);
  float* f2sT   = (float*)alloc((size_t)128*64*4);
  float* f2pT   = (float*)alloc((size_t)128*64*4);
  short* featb  = (short*)alloc((size_t)512*256*2);
  float* gatingb= (float*)alloc((size_t)512*12*4);
  float* moebuf = (float*)alloc((size_t)512*256*4);
  float* featf  = (float*)alloc((size_t)512*256*4);
  short* a1     = (short*)alloc((size_t)512*400*128*2);
  short* a2     = (short*)alloc((size_t)512*200*256*2);
  short* xgbuf  = (short*)alloc((size_t)200*512*1024*2);
  short* h0seq  = a1;  // a1 dead after conv2

  // prep
  prep_convw<<<(7*128*96 + 255)/256, 256, 0, stream>>>(conv1_w, conv1_b, bn1_g, bn1_b, bn1_m, bn1_v, w1T, b1c, 128, 80, 96);
  prep_convw<<<(7*256*128 + 255)/256, 256, 0, stream>>>(conv2_w, conv2_b, bn2_g, bn2_b, bn2_m, bn2_v, w2T, b2c, 256, 128, 128);
  cast_f32_bf16<<<512, 256, 0, stream>>>(wih0, wih0b, 1024*256);
  cast_f32_bf16<<<512, 256, 0, stream>>>(whh0, whh0b, 1024*256);
  cast_f32_bf16<<<512, 256, 0, stream>>>(wih1, wih1b, 1024*256);
  cast_f32_bf16<<<512, 256, 0, stream>>>(whh1, whh1b, 1024*256);
  quant_whh<<<768, 64, 0, stream>>>(whh0, wq8_0, invs0);
  quant_whh<<<768, 64, 0, stream>>>(whh1, wq8_1, invs1);
  add_f32<<<4, 256, 0, stream>>>(bih0, bhh0, bias0, 1024);
  add_f32<<<4, 256, 0, stream>>>(bih1, bhh1, bias1, 1024);
  transp_k<<<12*4*8, 256, 0, stream>>>(exp_w1, eW1T, 12, 256, 512);
  transp_k<<<12*8*4, 256, 0, stream>>>(exp_w2, eW2T, 12, 512, 256);
  transpf<<<(128*256 + 255)/256, 256, 0, stream>>>(fc1s_w, f1sT, 128, 256);
  transpf<<<(128*256 + 255)/256, 256, 0, stream>>>(fc1p_w, f1pT, 128, 256);
  transpf<<<(64*128 + 255)/256, 256, 0, stream>>>(fc2s_w, f2sT, 64, 128);
  transpf<<<(64*128 + 255)/256, 256, 0, stream>>>(fc2p_w, f2pT, 64, 128);

  // pipeline
  conv1_k<<<dim3(10, 512), 512, 0, stream>>>(x, w1T, b1c, a1);
  conv2_k<<<dim3(5, 512), 512, 0, stream>>>(a1, w2T, b2c, a2);
  xg_k<<<800, 512, 0, stream>>>(a2, wih0b, bias0, xgbuf, 0);
  lstm_k<<<32, 512, 0, stream>>>(xgbuf, whh0b, wq8_0, invs0, h0seq, nullptr, 0);
  xg_k<<<800, 512, 0, stream>>>(h0seq, wih1b, bias1, xgbuf, 1);
  lstm_k<<<32, 512, 0, stream>>>(xgbuf, whh1b, wq8_1, invs1, nullptr, featf, 1);
  gating_k<<<512, 64, 0, stream>>>(featf, gate_w, gate_b, gbn_g, gbn_b, gbn_m, gbn_v, gatingb, featb);
  hipMemsetAsync(moebuf, 0, (size_t)512*256*4, stream);
  moe_k<<<dim3(12, 16), 256, 0, stream>>>(featb, eW1T, exp_b1, eW2T, exp_b2, gatingb, moebuf);
  tower_k<<<32, 256, 0, stream>>>(moebuf,
      f1sT, fc1s_b, f2sT, fc2s_b, fc3s_w, fc3s_b,
      f1pT, fc1p_b, f2pT, fc2p_b, fc3p_w, fc3p_b,
      head_w, head_b, out);
}